// Round 17
// baseline (6335.161 us; speedup 1.0000x reference)
//
#include <hip/hip_runtime.h>
#include <hip/hip_bf16.h>

// Particle-filter VAE ELBO, MI355X single-fused-kernel implementation.
// Round 17: r16 base (PASS, 4.55ms). Deltas:
//  (1) RNG(t+1) moved into phase C with double-buffered sEB[2]: hashes fill
//      C's dependency-stall slots; FA shrinks to resample|x/Kx|wv. Prologue
//      generates eps(0) and eps(1). Counter mapping unchanged.
//  (2) exp2 folding: n/wv staged with 2*log2(e) scale; tanh = 1-2/(2^d+1)
//      (v_exp_f32 is natively 2^x -> drops one mul per tanh).
// Everything else byte-identical to r16.

#define WS_KG    0
#define WS_OMA   4096
#define WS_L     4608
#define WS_RSTDZ 5120
#define WS_RSTDX 5152
#define WS_CONST 5280

#define LOG2PI_F 1.8378770664093453f
#define TWO_LOG2E 2.8853900817779268f

typedef __attribute__((ext_vector_type(8))) short short8v;
typedef __attribute__((ext_vector_type(4))) float float4v;
typedef __attribute__((ext_vector_type(4))) unsigned uint4v;

#define MFMA32(a, b, c) \
  __builtin_amdgcn_mfma_f32_16x16x32_bf16((a), (b), (c), 0, 0, 0)

__device__ __forceinline__ unsigned rotl32(unsigned v, int r) {
  return (v << r) | (v >> (32 - r));
}

// Threefry-2x32, 20 rounds.
__device__ __forceinline__ void tf2x32(unsigned k0, unsigned k1,
                                       unsigned c0, unsigned c1,
                                       unsigned& o0, unsigned& o1) {
  unsigned ks2 = k0 ^ k1 ^ 0x1BD11BDAu;
  unsigned x0 = c0 + k0, x1 = c1 + k1;
#define TF_R4(ra, rb, rc, rd) \
  x0 += x1; x1 = rotl32(x1, ra); x1 ^= x0; \
  x0 += x1; x1 = rotl32(x1, rb); x1 ^= x0; \
  x0 += x1; x1 = rotl32(x1, rc); x1 ^= x0; \
  x0 += x1; x1 = rotl32(x1, rd); x1 ^= x0;
  TF_R4(13, 15, 26, 6)  x0 += k1;  x1 += ks2 + 1u;
  TF_R4(17, 29, 16, 24) x0 += ks2; x1 += k0 + 2u;
  TF_R4(13, 15, 26, 6)  x0 += k0;  x1 += k1 + 3u;
  TF_R4(17, 29, 16, 24) x0 += k1;  x1 += ks2 + 4u;
  TF_R4(13, 15, 26, 6)  x0 += ks2; x1 += k0 + 5u;
#undef TF_R4
  o0 = x0; o1 = x1;
}

// XLA ErfInv32 polynomial (Giles).
__device__ __forceinline__ float erfinv_f(float x) {
  float w = -log1pf(-x * x);
  float p;
  if (w < 5.0f) {
    w -= 2.5f;
    p = 2.81022636e-08f;
    p = fmaf(p, w, 3.43273939e-07f);
    p = fmaf(p, w, -3.5233877e-06f);
    p = fmaf(p, w, -4.39150654e-06f);
    p = fmaf(p, w, 0.00021858087f);
    p = fmaf(p, w, -0.00125372503f);
    p = fmaf(p, w, -0.00417768164f);
    p = fmaf(p, w, 0.246640727f);
    p = fmaf(p, w, 1.50140941f);
  } else {
    w = sqrtf(w) - 3.0f;
    p = -0.000200214257f;
    p = fmaf(p, w, 0.000100950558f);
    p = fmaf(p, w, 0.00134934322f);
    p = fmaf(p, w, -0.00367342844f);
    p = fmaf(p, w, 0.00573950773f);
    p = fmaf(p, w, -0.0076224613f);
    p = fmaf(p, w, 0.00943887047f);
    p = fmaf(p, w, 1.00167406f);
    p = fmaf(p, w, 2.83297682f);
  }
  return p * x;
}

__device__ __forceinline__ float normal_from_bits(unsigned bits) {
  float f = __uint_as_float((bits >> 9) | 0x3f800000u) - 1.0f;  // [0,1)
  const float lo = -0.99999994f;
  float uu = fmaxf(lo, fmaf(f, 2.0f, lo));
  return 1.41421354f * erfinv_f(uu);
}

// input pre-scaled by 2*log2(e): tanh(x) with d = 2x*log2(e) -> 2^d = e^{2x}
__device__ __forceinline__ float tanh_fast2e(float d) {
  float e = exp2f(d);
  return 1.0f - 2.0f * __builtin_amdgcn_rcpf(e + 1.0f);
}

// f32 -> bf16 bits, round-to-nearest-even (cold paths).
__device__ __forceinline__ short f2bf(float f) {
  unsigned u = __float_as_uint(f);
  unsigned r = (u + 0x7fffu + ((u >> 16) & 1u)) >> 16;
  return (short)r;
}

__device__ __forceinline__ unsigned packbf(float a, float b) {
  return (unsigned)(unsigned short)f2bf(a) |
         ((unsigned)(unsigned short)f2bf(b) << 16);
}

// hot pack: single HW instruction, RNE.
__device__ __forceinline__ unsigned cvtpk(float a, float b) {
  unsigned r;
  asm("v_cvt_pk_bf16_f32 %0, %1, %2" : "=v"(r) : "v"(a), "v"(b));
  return r;
}

__device__ __forceinline__ short8v mk8(unsigned a, unsigned b,
                                       unsigned c, unsigned d) {
  uint4v u = {a, b, c, d};
  return __builtin_bit_cast(short8v, u);
}

// ---------------- precompute kernel: Kalman quantities into ws --------------
__global__ void precomp_kernel(const float* __restrict__ Rz,
                               const float* __restrict__ Rz0,
                               const float* __restrict__ Rx,
                               const float* __restrict__ Bobs,
                               float* __restrict__ ws) {
  __shared__ float svarx[128];
  __shared__ float svarz[16];
  __shared__ float sprec[16][16];
  __shared__ float saug[16][32];
  __shared__ float svq[16][16];
  __shared__ float sLm[16][16];
  __shared__ float skg[16][128];
  const int tid = threadIdx.x;  // 256 threads

  if (tid < 128) {
    float r = Rx[tid];
    svarx[tid] = fmaxf(r * r, 1e-8f);
    ws[WS_RSTDX + tid] = 1.0f / fmaxf(fabsf(r), 1e-4f);
  }
  if (tid == 0) {
    float a = 0.0f;
    for (int xx = 0; xx < 128; ++xx) a += logf(fmaxf(fabsf(Rx[xx]), 1e-4f));
    ws[WS_CONST + 0] = -a - 0.5f * 128.0f * LOG2PI_F;
  }
  __syncthreads();

  for (int set = 0; set < 2; ++set) {
    const float* Rzp = (set == 0) ? Rz0 : Rz;
    if (tid < 16) {
      float v = Rzp[tid] * Rzp[tid] + 1e-8f;
      svarz[tid] = v;
      ws[WS_RSTDZ + set * 16 + tid] = 1.0f / sqrtf(v);
    }
    __syncthreads();
    {
      int z1 = tid >> 4, z2 = tid & 15;
      float a = 0.0f;
      for (int xx = 0; xx < 128; ++xx)
        a += Bobs[z1 * 128 + xx] * Bobs[z2 * 128 + xx] / svarx[xx];
      if (z1 == z2) a += 1.0f / svarz[z1];
      sprec[z1][z2] = a;
    }
    __syncthreads();
    if (tid == 0) {
      for (int r = 0; r < 16; ++r)
        for (int c2 = 0; c2 < 32; ++c2)
          saug[r][c2] = (c2 < 16) ? sprec[r][c2] : ((c2 - 16 == r) ? 1.0f : 0.0f);
      for (int p = 0; p < 16; ++p) {
        float ip = 1.0f / saug[p][p];
        for (int c2 = 0; c2 < 32; ++c2) saug[p][c2] *= ip;
        for (int r = 0; r < 16; ++r) if (r != p) {
          float f = saug[r][p];
          for (int c2 = 0; c2 < 32; ++c2) saug[r][c2] -= f * saug[p][c2];
        }
      }
      for (int r = 0; r < 16; ++r)
        for (int c2 = 0; c2 < 16; ++c2)
          svq[r][c2] = 0.5f * (saug[r][16 + c2] + saug[c2][16 + r]) +
                       ((r == c2) ? 1e-8f : 0.0f);
      for (int j = 0; j < 16; ++j) {
        float d = svq[j][j];
        for (int s = 0; s < j; ++s) d -= sLm[j][s] * sLm[j][s];
        float dj = sqrtf(d);
        sLm[j][j] = dj;
        for (int r = j + 1; r < 16; ++r) {
          float a = svq[r][j];
          for (int s = 0; s < j; ++s) a -= sLm[r][s] * sLm[j][s];
          sLm[r][j] = a / dj;
        }
        for (int r = 0; r < j; ++r) sLm[r][j] = 0.0f;
      }
      float cc = 0.0f;
      for (int j = 0; j < 16; ++j) cc += logf(sLm[j][j]) - logf(sqrtf(svarz[j]));
      ws[WS_CONST + 1 + set] = cc;
      for (int r = 0; r < 16; ++r)
        for (int c2 = 0; c2 < 16; ++c2)
          ws[WS_L + set * 256 + r * 16 + c2] = sLm[r][c2];
    }
    __syncthreads();
    for (int o = tid; o < 2048; o += 256) {
      int z = o >> 7, xx = o & 127;
      float a = 0.0f;
      for (int s = 0; s < 16; ++s) a += saug[z][16 + s] * Bobs[s * 128 + xx];
      a /= svarx[xx];
      skg[z][xx] = a;
      ws[WS_KG + set * 2048 + o] = a;
    }
    __syncthreads();
    {
      int z = tid >> 4, s = tid & 15;
      float a = 0.0f;
      for (int xx = 0; xx < 128; ++xx) a += skg[z][xx] * Bobs[s * 128 + xx];
      ws[WS_OMA + set * 256 + tid] = ((z == s) ? 1.0f : 0.0f) - a;
    }
    __syncthreads();
  }
}

// ---------------- main particle-filter kernel: 1 block = 1 batch -----------
__global__ __launch_bounds__(512, 1) void pf_kernel(
    const float* __restrict__ xg, const float* __restrict__ ug,
    const float* __restrict__ Bobs, const float* __restrict__ Obias,
    const float* __restrict__ mg, const float* __restrict__ ng,
    const float* __restrict__ Wug, const float* __restrict__ hg,
    const float* __restrict__ W0g, const float* __restrict__ b0g,
    const float* __restrict__ ws, float* __restrict__ out) {
  __shared__ float sPart[8][128][20];    // GEMM2 partials [wave][p][z], padded
  __shared__ short8v sBF[8][32];         // B_obs^T E-A-frags
  __shared__ unsigned sKeys[512][4];     // per-step {k1a,k1b,k2a,k2b}
  __shared__ __align__(16) unsigned qnA[128 * 12];  // bf16 state, ping
  __shared__ __align__(16) unsigned qnB[128 * 12];  // bf16 state, pong
  __shared__ __align__(16) unsigned sEB[2][128 * 12];  // eps bf16, dbuf
  __shared__ __align__(16) float sWV[512];          // 2log2e*(Wu@v + h)
  __shared__ __align__(16) float sXT[128];          // x_t - Obs_bias
  __shared__ __align__(16) float sXR[128];          // sXT * sRX
  __shared__ __align__(16) float sRX[128];          // 1/std_x
  __shared__ __align__(16) float sKx[16];
  __shared__ int   sIDX[128];
  __shared__ float sLLC[4][128];         // prologue partials only
  __shared__ float sLLD[128];            // per-particle ll_pz-ll_qz total
  __shared__ float sLLE[128];            // obs quad total

  const int tid  = threadIdx.x;
  const int b    = blockIdx.x;
  const int lane = tid & 63;
  const int wid  = tid >> 6;       // 0..7
  const int q    = lane >> 4;      // 0..3
  const int r16  = lane & 15;

  const short8v zero8 = {0, 0, 0, 0, 0, 0, 0, 0};
  const float4v zero4 = {0.f, 0.f, 0.f, 0.f};

  // ---------------- init staging ----------------
  if (tid < 256) {
    int xt = tid >> 5, sl2 = tid & 31, qq = sl2 >> 4, rr = sl2 & 15;
    short8v v;
#pragma unroll
    for (int i = 0; i < 8; ++i)
      v[i] = f2bf(Bobs[(size_t)(qq * 8 + i) * 128 + xt * 16 + rr]);
    sBF[xt][sl2] = v;
  }
  {  // per-step threefry keys
    int t = tid;
    unsigned kt0, kt1;
    tf2x32(0u, 42u, 0u, (unsigned)t, kt0, kt1);
    unsigned k1a = 0, k1b = 0, k2a = kt0, k2b = kt1;
    if (t > 0) {
      tf2x32(kt0, kt1, 0u, 0u, k1a, k1b);
      tf2x32(kt0, kt1, 0u, 1u, k2a, k2b);
    }
    sKeys[t][0] = k1a; sKeys[t][1] = k1b; sKeys[t][2] = k2a; sKeys[t][3] = k2b;
  }
  if (tid < 128) sRX[tid] = ws[WS_RSTDX + tid];

  // ---- persistent per-lane register fragments ----
  short8v a1f[4];
#pragma unroll
  for (int j = 0; j < 4; ++j) {
    short8v v = {0, 0, 0, 0, 0, 0, 0, 0};
    const float* src = ng + (size_t)((wid + 8 * j) * 16 + r16) * 16 + 4 * q;
#pragma unroll
    for (int i = 0; i < 4; ++i) v[i] = f2bf(TWO_LOG2E * src[i]);
    a1f[j] = v;
  }
  short8v a2f[2];
#pragma unroll
  for (int P = 0; P < 2; ++P) {
    short8v v;
#pragma unroll
    for (int i = 0; i < 4; ++i) {
      v[i]     = f2bf(mg[(size_t)((wid + 16 * P) * 16 + 4 * q + i) * 16 + r16]);
      v[4 + i] = f2bf(mg[(size_t)((wid + 16 * P + 8) * 16 + 4 * q + i) * 16 + r16]);
    }
    a2f[P] = v;
  }
  short8v aD;
  {
    const float* adsrc = (q < 2) ? (ws + WS_OMA + 256) : (ws + WS_L + 256);
    const int kb = (q & 1) * 8;
#pragma unroll
    for (int i = 0; i < 8; ++i)
      aD[i] = f2bf(adsrc[r16 * 16 + kb + i]);
  }
  float rsz4[4];
#pragma unroll
  for (int i = 0; i < 4; ++i) rsz4[i] = ws[WS_RSTDZ + 16 + 4 * q + i];

  const float cobs = ws[WS_CONST + 0];
  const float cc0  = ws[WS_CONST + 1];
  const float cc1  = ws[WS_CONST + 2];
  __syncthreads();

  float elbo = 0.0f;
  const int p    = wid * 16 + r16;   // this lane's particle in D/E
  const int srcA = 32 * q + r16;     // D/E fragment-assembly sources (q<2)
  const int srcB = srcA + 16;
  const int sl   = q * 16 + r16;

  // ======================= t = 0 prologue ==================================
  {
    if (wid == 1) {
#pragma unroll
      for (int h2 = 0; h2 < 2; ++h2) {
        int xx = lane + 64 * h2;
        float xv = xg[((size_t)b * 128 + xx) * 512] - Obias[xx];
        sXT[xx] = xv;
        sXR[xx] = xv * sRX[xx];
      }
    }
    {  // RNG: eps(0) -> sEB[0], eps(1) -> sEB[1] (both-outputs mapping)
#pragma unroll
      for (int st = 0; st < 2; ++st) {
        short* ebw = (short*)sEB[st];
        unsigned k2a = sKeys[st][2], k2b = sKeys[st][3];
#pragma unroll
        for (int j = 0; j < 2; ++j) {
          int c = tid + 512 * j;   // 0..1023
          unsigned o0, o1;
          tf2x32(k2a, k2b, 0u, (unsigned)(b * 2048 + c), o0, o1);
          int f0 = 2 * c, f1 = 2 * c + 1;
          ebw[(f0 & 127) * 24 + (f0 >> 7)] = f2bf(normal_from_bits(o0));
          ebw[(f1 & 127) * 24 + (f1 >> 7)] = f2bf(normal_from_bits(o1));
        }
      }
    }
    __syncthreads();

    // ---- phase D0 (scalar, cold path; eps from sEB[0]) ----
    {
      const int kk = tid & 127, zg = tid >> 7;  // zg 0..3
      float ep[16];
#pragma unroll
      for (int w2 = 0; w2 < 8; ++w2) {
        unsigned uw = sEB[0][kk * 12 + w2];
        ep[2 * w2]     = __uint_as_float(uw << 16);
        ep[2 * w2 + 1] = __uint_as_float(uw & 0xffff0000u);
      }
      float part = 0.0f;
      if (zg == 0) {
        float qd = 0.0f;
#pragma unroll
        for (int s = 0; s < 16; ++s) qd = fmaf(ep[s], ep[s], qd);
        part = 0.5f * qd;
      }
      float v0[8];
#pragma unroll
      for (int d = 0; d < 8; ++d) v0[d] = ug[((size_t)b * 8 + d) * 512];
      float pm0[16];
#pragma unroll
      for (int s = 0; s < 16; ++s) {
        float a = b0g[s];
#pragma unroll
        for (int d = 0; d < 8; ++d) a = fmaf(W0g[s * 8 + d], v0[d], a);
        pm0[s] = a;
      }
      const float* Kg0p = ws + WS_KG;
      const float* omap = ws + WS_OMA;
      const float* Lp   = ws + WS_L;
      const float* rsz  = ws + WS_RSTDZ;
      float qnv[4];
#pragma unroll
      for (int zi = 0; zi < 4; ++zi) {
        int z = zg * 4 + zi;
        float mq = 0.0f;
        for (int xx = 0; xx < 128; ++xx)
          mq = fmaf(Kg0p[z * 128 + xx], sXT[xx], mq);
#pragma unroll
        for (int s = 0; s < 16; ++s) mq = fmaf(omap[z * 16 + s], pm0[s], mq);
        float qn = mq;
#pragma unroll
        for (int s = 0; s < 16; ++s) qn = fmaf(Lp[z * 16 + s], ep[s], qn);
        qnv[zi] = qn;
        float pz = b0g[z];
#pragma unroll
        for (int d = 0; d < 8; ++d) pz = fmaf(W0g[z * 8 + d], v0[d], pz);
        float r = (qn - pz) * rsz[z];
        part = fmaf(-0.5f * r, r, part);
      }
      qnA[kk * 12 + zg * 2 + 0] = packbf(qnv[0], qnv[1]);
      qnA[kk * 12 + zg * 2 + 1] = packbf(qnv[2], qnv[3]);
      sLLC[zg][kk] = part;
    }
    __syncthreads();

    // ---- phase E0 (+ sLLD reduction) ----
    {
      short8v bq = zero8;
      if (q < 2) bq = *(const short8v*)&qnA[p * 12 + q * 4];
      float ea = 0.0f;
#pragma unroll
      for (int xt = 0; xt < 8; ++xt) {
        short8v ab = (q < 2) ? sBF[xt][sl] : zero8;
        float4v d = MFMA32(ab, bq, zero4);
        float4v xr = *(const float4v*)&sXR[xt * 16 + q * 4];
        float4v rx = *(const float4v*)&sRX[xt * 16 + q * 4];
        float d0 = xr.x - d.x * rx.x; ea = fmaf(d0, d0, ea);
        float d1 = xr.y - d.y * rx.y; ea = fmaf(d1, d1, ea);
        float d2 = xr.z - d.z * rx.z; ea = fmaf(d2, d2, ea);
        float d3 = xr.w - d.w * rx.w; ea = fmaf(d3, d3, ea);
      }
      ea += __shfl_xor(ea, 16, 64);
      ea += __shfl_xor(ea, 32, 64);
      if (q == 0) sLLE[p] = ea;
      if (tid < 128)
        sLLD[tid] = sLLC[0][tid] + sLLC[1][tid] + sLLC[2][tid] + sLLC[3][tid];
    }
    __syncthreads();
  }

  // ======================= hot loop: t = 1..511 ============================
  for (int t = 1; t < 512; ++t) {
    const unsigned* qnPrev = (t & 1) ? qnA : qnB;
    unsigned* qnCur = (t & 1) ? qnB : qnA;
    const unsigned* ebR = sEB[t & 1];           // eps(t)

    // ===== phase FA: F(t-1)+resample (w0) | x/Kx (w1) | wv (w2) ============
    if (wid == 0) {
      float cc = (t == 1) ? cc0 : cc1;
      float lw0 = 0, lw1 = 0;
#pragma unroll
      for (int half = 0; half < 2; ++half) {
        int j = 2 * lane + half;
        float v = -0.5f * sLLE[j] + cobs + cc + sLLD[j];
        if (half) lw1 = v; else lw0 = v;
      }
      float mx = fmaxf(lw0, lw1);
#pragma unroll
      for (int d = 32; d >= 1; d >>= 1) mx = fmaxf(mx, __shfl_xor(mx, d, 64));
      float ea = __expf(lw0 - mx), eb = __expf(lw1 - mx);
      float se = ea + eb;
#pragma unroll
      for (int d = 32; d >= 1; d >>= 1) se += __shfl_xor(se, d, 64);
      elbo += logf(se) + mx - 4.85203026f;  // log(128)

      float run = ea + eb;
#pragma unroll
      for (int d = 1; d < 64; d <<= 1) {
        float v = __shfl_up(run, (unsigned)d, 64);
        if (lane >= d) run += v;
      }
      float tot = __shfl(run, 63, 64);
      float inv = 1.0f / tot;
      float c0 = (run - eb) * inv;
      float c1 = run * inv;
      unsigned o0, o1;
      tf2x32(sKeys[t][0], sKeys[t][1], 0u, (unsigned)b, o0, o1);
      unsigned bits = o0 ^ o1;
      float u0 = __uint_as_float((bits >> 9) | 0x3f800000u) - 1.0f;
      int S0, S1;
      {
        int s = (int)fmaf(c0, 128.0f, -u0);
        s = (s < 0) ? 0 : ((s > 128) ? 128 : s);
        while (s > 0   && (u0 + (float)(s - 1)) * 0.0078125f >  c0) --s;
        while (s < 128 && (u0 + (float)s)       * 0.0078125f <= c0) ++s;
        S0 = s;
        s = (int)fmaf(c1, 128.0f, -u0);
        s = (s < 0) ? 0 : ((s > 128) ? 128 : s);
        while (s > 0   && (u0 + (float)(s - 1)) * 0.0078125f >  c1) --s;
        while (s < 128 && (u0 + (float)s)       * 0.0078125f <= c1) ++s;
        S1 = s;
      }
      if (lane == 63) S1 = 128;
      int Sp = __shfl_up(S1, 1, 64);
      if (lane == 0) Sp = 0;
      if (S0 > S1) S0 = S1;
      if (Sp > S0) Sp = S0;
      for (int j = Sp; j < S0; ++j) sIDX[j] = 2 * lane;
      for (int j = S0; j < S1; ++j) sIDX[j] = 2 * lane + 1;
    } else if (wid == 1) {
#pragma unroll
      for (int h2 = 0; h2 < 2; ++h2) {
        int xx = lane + 64 * h2;
        float xv = xg[((size_t)b * 128 + xx) * 512 + t] - Obias[xx];
        sXT[xx] = xv;
        sXR[xx] = xv * sRX[xx];
      }
      int z = lane >> 2, xq = lane & 3;
      const float* Kgp = ws + WS_KG + 2048 + z * 128;
      float a = 0.0f;
      for (int jj = 0; jj < 32; ++jj) {
        int xx = xq + 4 * jj;
        a = fmaf(Kgp[xx], sXT[xx], a);
      }
      a += __shfl_xor(a, 1, 64);
      a += __shfl_xor(a, 2, 64);
      if (xq == 0) sKx[z] = a;
    } else if (wid == 2) {  // wv stage (pre-scaled by 2*log2e)
      float v[8];
#pragma unroll
      for (int d = 0; d < 8; ++d) v[d] = ug[((size_t)b * 8 + d) * 512 + (t - 1)];
#pragma unroll
      for (int qq = 0; qq < 8; ++qq) {
        int N = lane + 64 * qq;
        const float4* wr = (const float4*)&Wug[N * 8];
        float4 wa = wr[0], wb = wr[1];
        float a = hg[N];
        a = fmaf(wa.x, v[0], a); a = fmaf(wa.y, v[1], a);
        a = fmaf(wa.z, v[2], a); a = fmaf(wa.w, v[3], a);
        a = fmaf(wb.x, v[4], a); a = fmaf(wb.y, v[5], a);
        a = fmaf(wb.z, v[6], a); a = fmaf(wb.w, v[7], a);
        sWV[N] = TWO_LOG2E * a;
      }
    }
    __syncthreads();

    // ===== phase C: transition + RNG(t+1) (fills stall slots) ==============
    {
      // RNG(t+1): 2 hashes/thread into sEB[(t+1)&1] (disjoint from ebR)
      if (t < 511) {
        short* ebw = (short*)sEB[(t + 1) & 1];
        unsigned k2a = sKeys[t + 1][2], k2b = sKeys[t + 1][3];
#pragma unroll
        for (int j = 0; j < 2; ++j) {
          int c = tid + 512 * j;
          unsigned o0, o1;
          tf2x32(k2a, k2b, 0u, (unsigned)(b * 2048 + c), o0, o1);
          int f0 = 2 * c, f1 = 2 * c + 1;
          ebw[(f0 & 127) * 24 + (f0 >> 7)] = f2bf(normal_from_bits(o0));
          ebw[(f1 & 127) * 24 + (f1 >> 7)] = f2bf(normal_from_bits(o1));
        }
      }
      float4v cin[4];
#pragma unroll
      for (int j = 0; j < 4; ++j)
        cin[j] = *(const float4v*)&sWV[(wid + 8 * j) * 16 + 4 * q];
      uint2 zw8[8];
#pragma unroll
      for (int pt = 0; pt < 8; ++pt) {
        int idxp = sIDX[pt * 16 + r16];
        zw8[pt] = *(const uint2*)&qnPrev[idxp * 12 + 2 * q];
      }
#pragma unroll
      for (int pt = 0; pt < 8; ++pt) {
        const int pp = pt * 16 + r16;
        short8v bz = mk8(zw8[pt].x, zw8[pt].y, 0u, 0u);
        float4v d1a = MFMA32(a1f[0], bz, cin[0]);
        float4v d1b = MFMA32(a1f[1], bz, cin[1]);
        float4v d1c = MFMA32(a1f[2], bz, cin[2]);
        float4v d1d = MFMA32(a1f[3], bz, cin[3]);
        unsigned pa0 = cvtpk(tanh_fast2e(d1a.x), tanh_fast2e(d1a.y));
        unsigned pa1 = cvtpk(tanh_fast2e(d1a.z), tanh_fast2e(d1a.w));
        unsigned pb0 = cvtpk(tanh_fast2e(d1b.x), tanh_fast2e(d1b.y));
        unsigned pb1 = cvtpk(tanh_fast2e(d1b.z), tanh_fast2e(d1b.w));
        unsigned pc0 = cvtpk(tanh_fast2e(d1c.x), tanh_fast2e(d1c.y));
        unsigned pc1 = cvtpk(tanh_fast2e(d1c.z), tanh_fast2e(d1c.w));
        unsigned pd0 = cvtpk(tanh_fast2e(d1d.x), tanh_fast2e(d1d.y));
        unsigned pd1 = cvtpk(tanh_fast2e(d1d.z), tanh_fast2e(d1d.w));
        float4v a8 = MFMA32(a2f[0], mk8(pa0, pa1, pb0, pb1), zero4);
        a8 = MFMA32(a2f[1], mk8(pc0, pc1, pd0, pd1), a8);
        *(float4v*)&sPart[wid][pp][4 * q] = a8;
      }
    }
    __syncthreads();

    // ===== phase DE: reduce + proposal MFMA + obs MFMA =====================
    {
      float4v red = zero4;
#pragma unroll
      for (int wv = 0; wv < 8; ++wv)
        red += *(const float4v*)&sPart[wv][p][4 * q];
      const int idxp = sIDX[p];
      uint2 zw = *(const uint2*)&qnPrev[idxp * 12 + 2 * q];
      float zl0 = __uint_as_float(zw.x << 16);
      float zl1 = __uint_as_float(zw.x & 0xffff0000u);
      float zl2 = __uint_as_float(zw.y << 16);
      float zl3 = __uint_as_float(zw.y & 0xffff0000u);
      float pm0 = fmaf(0.1f, red.x, 0.9f * zl0);
      float pm1 = fmaf(0.1f, red.y, 0.9f * zl1);
      float pm2 = fmaf(0.1f, red.z, 0.9f * zl2);
      float pm3 = fmaf(0.1f, red.w, 0.9f * zl3);

      unsigned w01 = cvtpk(pm0, pm1), w23 = cvtpk(pm2, pm3);
      unsigned bA0 = (unsigned)__shfl((int)w01, srcA, 64);
      unsigned bA1 = (unsigned)__shfl((int)w23, srcA, 64);
      unsigned bB0 = (unsigned)__shfl((int)w01, srcB, 64);
      unsigned bB1 = (unsigned)__shfl((int)w23, srcB, 64);
      short8v bw;
      if (q < 2) {
        uint4v uu = {bA0, bA1, bB0, bB1};
        bw = __builtin_bit_cast(short8v, uu);
      } else {
        bw = *(const short8v*)&ebR[p * 12 + (q - 2) * 4];
      }
      float4v cinD = *(const float4v*)&sKx[4 * q];
      float4v aq = MFMA32(aD, bw, cinD);
      float part = 0.0f;
      if (q >= 2) {
        uint4v uw = __builtin_bit_cast(uint4v, bw);
        float e0 = __uint_as_float(uw.x << 16);
        float e1 = __uint_as_float(uw.x & 0xffff0000u);
        float e2 = __uint_as_float(uw.y << 16);
        float e3 = __uint_as_float(uw.y & 0xffff0000u);
        float e4 = __uint_as_float(uw.z << 16);
        float e5 = __uint_as_float(uw.z & 0xffff0000u);
        float e6 = __uint_as_float(uw.w << 16);
        float e7 = __uint_as_float(uw.w & 0xffff0000u);
        float s2 = 0.0f;
        s2 = fmaf(e0, e0, s2); s2 = fmaf(e1, e1, s2);
        s2 = fmaf(e2, e2, s2); s2 = fmaf(e3, e3, s2);
        s2 = fmaf(e4, e4, s2); s2 = fmaf(e5, e5, s2);
        s2 = fmaf(e6, e6, s2); s2 = fmaf(e7, e7, s2);
        part = 0.5f * s2;
      }
      float r0 = (aq.x - pm0) * rsz4[0];
      float r1 = (aq.y - pm1) * rsz4[1];
      float r2 = (aq.z - pm2) * rsz4[2];
      float r3 = (aq.w - pm3) * rsz4[3];
      part = fmaf(-0.5f * r0, r0, part);
      part = fmaf(-0.5f * r1, r1, part);
      part = fmaf(-0.5f * r2, r2, part);
      part = fmaf(-0.5f * r3, r3, part);
      unsigned y01 = cvtpk(aq.x, aq.y), y23 = cvtpk(aq.z, aq.w);
      *(uint2*)&qnCur[p * 12 + 2 * q] = make_uint2(y01, y23);
      part += __shfl_xor(part, 16, 64);
      part += __shfl_xor(part, 32, 64);
      if (q == 0) sLLD[p] = part;

      unsigned qA0 = (unsigned)__shfl((int)y01, srcA, 64);
      unsigned qA1 = (unsigned)__shfl((int)y23, srcA, 64);
      unsigned qB0 = (unsigned)__shfl((int)y01, srcB, 64);
      unsigned qB1 = (unsigned)__shfl((int)y23, srcB, 64);
      short8v bq = zero8;
      if (q < 2) {
        uint4v uu = {qA0, qA1, qB0, qB1};
        bq = __builtin_bit_cast(short8v, uu);
      }
      float ea = 0.0f;
#pragma unroll
      for (int xt = 0; xt < 8; ++xt) {
        short8v ab = (q < 2) ? sBF[xt][sl] : zero8;
        float4v d = MFMA32(ab, bq, zero4);
        float4v xr = *(const float4v*)&sXR[xt * 16 + q * 4];
        float4v rx = *(const float4v*)&sRX[xt * 16 + q * 4];
        float d0 = xr.x - d.x * rx.x; ea = fmaf(d0, d0, ea);
        float d1 = xr.y - d.y * rx.y; ea = fmaf(d1, d1, ea);
        float d2 = xr.z - d.z * rx.z; ea = fmaf(d2, d2, ea);
        float d3 = xr.w - d.w * rx.w; ea = fmaf(d3, d3, ea);
      }
      ea += __shfl_xor(ea, 16, 64);
      ea += __shfl_xor(ea, 32, 64);
      if (q == 0) sLLE[p] = ea;
    }
    __syncthreads();
  }

  // ===== final F(511): elbo contribution only ==============================
  if (wid == 0) {
    float lw0 = 0, lw1 = 0;
#pragma unroll
    for (int half = 0; half < 2; ++half) {
      int j = 2 * lane + half;
      float v = -0.5f * sLLE[j] + cobs + cc1 + sLLD[j];
      if (half) lw1 = v; else lw0 = v;
    }
    float mx = fmaxf(lw0, lw1);
#pragma unroll
    for (int d = 32; d >= 1; d >>= 1) mx = fmaxf(mx, __shfl_xor(mx, d, 64));
    float se = __expf(lw0 - mx) + __expf(lw1 - mx);
#pragma unroll
    for (int d = 32; d >= 1; d >>= 1) se += __shfl_xor(se, d, 64);
    elbo += logf(se) + mx - 4.85203026f;
  }
  if (tid == 0) out[b] = -elbo * (1.0f / 512.0f);
}

extern "C" void kernel_launch(void* const* d_in, const int* in_sizes, int n_in,
                              void* d_out, int out_size, void* d_ws, size_t ws_size,
                              hipStream_t stream) {
  const float* x     = (const float*)d_in[0];
  const float* u     = (const float*)d_in[1];
  const float* R_z   = (const float*)d_in[2];
  const float* R_z0  = (const float*)d_in[3];
  const float* R_x   = (const float*)d_in[4];
  const float* B_obs = (const float*)d_in[5];
  const float* Obias = (const float*)d_in[6];
  const float* m     = (const float*)d_in[7];
  const float* n     = (const float*)d_in[8];
  const float* Wu    = (const float*)d_in[9];
  const float* h     = (const float*)d_in[10];
  const float* W0    = (const float*)d_in[11];
  const float* b0    = (const float*)d_in[12];
  float* ws = (float*)d_ws;
  float* outp = (float*)d_out;

  precomp_kernel<<<dim3(1), dim3(256), 0, stream>>>(R_z, R_z0, R_x, B_obs, ws);
  pf_kernel<<<dim3(128), dim3(512), 0, stream>>>(x, u, B_obs, Obias, m, n, Wu, h,
                                                 W0, b0, ws, outp);
}

// Round 18
// 5697.083 us; speedup vs baseline: 1.1120x; 1.1120x over previous
//
#include <hip/hip_runtime.h>
#include <hip/hip_bf16.h>

// Particle-filter VAE ELBO, MI355X single-fused-kernel implementation.
// Round 18: REVERT r17's RNG-in-C (regressed 4.55->6.03ms: lengthening the
// critical phase loses; wave-level specialization in FA was already hiding
// RNG under the serial resample). Keep only the exp2 folding. This is r16
// (PASS, 4.55ms) + tanh via exp2 with n/wv pre-scaled by 2*log2(e).

#define WS_KG    0
#define WS_OMA   4096
#define WS_L     4608
#define WS_RSTDZ 5120
#define WS_RSTDX 5152
#define WS_CONST 5280

#define LOG2PI_F 1.8378770664093453f
#define TWO_LOG2E 2.8853900817779268f

typedef __attribute__((ext_vector_type(8))) short short8v;
typedef __attribute__((ext_vector_type(4))) float float4v;
typedef __attribute__((ext_vector_type(4))) unsigned uint4v;

#define MFMA32(a, b, c) \
  __builtin_amdgcn_mfma_f32_16x16x32_bf16((a), (b), (c), 0, 0, 0)

__device__ __forceinline__ unsigned rotl32(unsigned v, int r) {
  return (v << r) | (v >> (32 - r));
}

// Threefry-2x32, 20 rounds.
__device__ __forceinline__ void tf2x32(unsigned k0, unsigned k1,
                                       unsigned c0, unsigned c1,
                                       unsigned& o0, unsigned& o1) {
  unsigned ks2 = k0 ^ k1 ^ 0x1BD11BDAu;
  unsigned x0 = c0 + k0, x1 = c1 + k1;
#define TF_R4(ra, rb, rc, rd) \
  x0 += x1; x1 = rotl32(x1, ra); x1 ^= x0; \
  x0 += x1; x1 = rotl32(x1, rb); x1 ^= x0; \
  x0 += x1; x1 = rotl32(x1, rc); x1 ^= x0; \
  x0 += x1; x1 = rotl32(x1, rd); x1 ^= x0;
  TF_R4(13, 15, 26, 6)  x0 += k1;  x1 += ks2 + 1u;
  TF_R4(17, 29, 16, 24) x0 += ks2; x1 += k0 + 2u;
  TF_R4(13, 15, 26, 6)  x0 += k0;  x1 += k1 + 3u;
  TF_R4(17, 29, 16, 24) x0 += k1;  x1 += ks2 + 4u;
  TF_R4(13, 15, 26, 6)  x0 += ks2; x1 += k0 + 5u;
#undef TF_R4
  o0 = x0; o1 = x1;
}

// XLA ErfInv32 polynomial (Giles).
__device__ __forceinline__ float erfinv_f(float x) {
  float w = -log1pf(-x * x);
  float p;
  if (w < 5.0f) {
    w -= 2.5f;
    p = 2.81022636e-08f;
    p = fmaf(p, w, 3.43273939e-07f);
    p = fmaf(p, w, -3.5233877e-06f);
    p = fmaf(p, w, -4.39150654e-06f);
    p = fmaf(p, w, 0.00021858087f);
    p = fmaf(p, w, -0.00125372503f);
    p = fmaf(p, w, -0.00417768164f);
    p = fmaf(p, w, 0.246640727f);
    p = fmaf(p, w, 1.50140941f);
  } else {
    w = sqrtf(w) - 3.0f;
    p = -0.000200214257f;
    p = fmaf(p, w, 0.000100950558f);
    p = fmaf(p, w, 0.00134934322f);
    p = fmaf(p, w, -0.00367342844f);
    p = fmaf(p, w, 0.00573950773f);
    p = fmaf(p, w, -0.0076224613f);
    p = fmaf(p, w, 0.00943887047f);
    p = fmaf(p, w, 1.00167406f);
    p = fmaf(p, w, 2.83297682f);
  }
  return p * x;
}

__device__ __forceinline__ float normal_from_bits(unsigned bits) {
  float f = __uint_as_float((bits >> 9) | 0x3f800000u) - 1.0f;  // [0,1)
  const float lo = -0.99999994f;
  float uu = fmaxf(lo, fmaf(f, 2.0f, lo));
  return 1.41421354f * erfinv_f(uu);
}

// input pre-scaled by 2*log2(e): tanh(x) with d = 2x*log2(e) -> 2^d = e^{2x}
__device__ __forceinline__ float tanh_fast2e(float d) {
  float e = exp2f(d);
  return 1.0f - 2.0f * __builtin_amdgcn_rcpf(e + 1.0f);
}

// f32 -> bf16 bits, round-to-nearest-even (cold paths).
__device__ __forceinline__ short f2bf(float f) {
  unsigned u = __float_as_uint(f);
  unsigned r = (u + 0x7fffu + ((u >> 16) & 1u)) >> 16;
  return (short)r;
}

__device__ __forceinline__ unsigned packbf(float a, float b) {
  return (unsigned)(unsigned short)f2bf(a) |
         ((unsigned)(unsigned short)f2bf(b) << 16);
}

// hot pack: single HW instruction, RNE.
__device__ __forceinline__ unsigned cvtpk(float a, float b) {
  unsigned r;
  asm("v_cvt_pk_bf16_f32 %0, %1, %2" : "=v"(r) : "v"(a), "v"(b));
  return r;
}

__device__ __forceinline__ short8v mk8(unsigned a, unsigned b,
                                       unsigned c, unsigned d) {
  uint4v u = {a, b, c, d};
  return __builtin_bit_cast(short8v, u);
}

// ---------------- precompute kernel: Kalman quantities into ws --------------
__global__ void precomp_kernel(const float* __restrict__ Rz,
                               const float* __restrict__ Rz0,
                               const float* __restrict__ Rx,
                               const float* __restrict__ Bobs,
                               float* __restrict__ ws) {
  __shared__ float svarx[128];
  __shared__ float svarz[16];
  __shared__ float sprec[16][16];
  __shared__ float saug[16][32];
  __shared__ float svq[16][16];
  __shared__ float sLm[16][16];
  __shared__ float skg[16][128];
  const int tid = threadIdx.x;  // 256 threads

  if (tid < 128) {
    float r = Rx[tid];
    svarx[tid] = fmaxf(r * r, 1e-8f);
    ws[WS_RSTDX + tid] = 1.0f / fmaxf(fabsf(r), 1e-4f);
  }
  if (tid == 0) {
    float a = 0.0f;
    for (int xx = 0; xx < 128; ++xx) a += logf(fmaxf(fabsf(Rx[xx]), 1e-4f));
    ws[WS_CONST + 0] = -a - 0.5f * 128.0f * LOG2PI_F;
  }
  __syncthreads();

  for (int set = 0; set < 2; ++set) {
    const float* Rzp = (set == 0) ? Rz0 : Rz;
    if (tid < 16) {
      float v = Rzp[tid] * Rzp[tid] + 1e-8f;
      svarz[tid] = v;
      ws[WS_RSTDZ + set * 16 + tid] = 1.0f / sqrtf(v);
    }
    __syncthreads();
    {
      int z1 = tid >> 4, z2 = tid & 15;
      float a = 0.0f;
      for (int xx = 0; xx < 128; ++xx)
        a += Bobs[z1 * 128 + xx] * Bobs[z2 * 128 + xx] / svarx[xx];
      if (z1 == z2) a += 1.0f / svarz[z1];
      sprec[z1][z2] = a;
    }
    __syncthreads();
    if (tid == 0) {
      for (int r = 0; r < 16; ++r)
        for (int c2 = 0; c2 < 32; ++c2)
          saug[r][c2] = (c2 < 16) ? sprec[r][c2] : ((c2 - 16 == r) ? 1.0f : 0.0f);
      for (int p = 0; p < 16; ++p) {
        float ip = 1.0f / saug[p][p];
        for (int c2 = 0; c2 < 32; ++c2) saug[p][c2] *= ip;
        for (int r = 0; r < 16; ++r) if (r != p) {
          float f = saug[r][p];
          for (int c2 = 0; c2 < 32; ++c2) saug[r][c2] -= f * saug[p][c2];
        }
      }
      for (int r = 0; r < 16; ++r)
        for (int c2 = 0; c2 < 16; ++c2)
          svq[r][c2] = 0.5f * (saug[r][16 + c2] + saug[c2][16 + r]) +
                       ((r == c2) ? 1e-8f : 0.0f);
      for (int j = 0; j < 16; ++j) {
        float d = svq[j][j];
        for (int s = 0; s < j; ++s) d -= sLm[j][s] * sLm[j][s];
        float dj = sqrtf(d);
        sLm[j][j] = dj;
        for (int r = j + 1; r < 16; ++r) {
          float a = svq[r][j];
          for (int s = 0; s < j; ++s) a -= sLm[r][s] * sLm[j][s];
          sLm[r][j] = a / dj;
        }
        for (int r = 0; r < j; ++r) sLm[r][j] = 0.0f;
      }
      float cc = 0.0f;
      for (int j = 0; j < 16; ++j) cc += logf(sLm[j][j]) - logf(sqrtf(svarz[j]));
      ws[WS_CONST + 1 + set] = cc;
      for (int r = 0; r < 16; ++r)
        for (int c2 = 0; c2 < 16; ++c2)
          ws[WS_L + set * 256 + r * 16 + c2] = sLm[r][c2];
    }
    __syncthreads();
    for (int o = tid; o < 2048; o += 256) {
      int z = o >> 7, xx = o & 127;
      float a = 0.0f;
      for (int s = 0; s < 16; ++s) a += saug[z][16 + s] * Bobs[s * 128 + xx];
      a /= svarx[xx];
      skg[z][xx] = a;
      ws[WS_KG + set * 2048 + o] = a;
    }
    __syncthreads();
    {
      int z = tid >> 4, s = tid & 15;
      float a = 0.0f;
      for (int xx = 0; xx < 128; ++xx) a += skg[z][xx] * Bobs[s * 128 + xx];
      ws[WS_OMA + set * 256 + tid] = ((z == s) ? 1.0f : 0.0f) - a;
    }
    __syncthreads();
  }
}

// ---------------- main particle-filter kernel: 1 block = 1 batch -----------
__global__ __launch_bounds__(512, 1) void pf_kernel(
    const float* __restrict__ xg, const float* __restrict__ ug,
    const float* __restrict__ Bobs, const float* __restrict__ Obias,
    const float* __restrict__ mg, const float* __restrict__ ng,
    const float* __restrict__ Wug, const float* __restrict__ hg,
    const float* __restrict__ W0g, const float* __restrict__ b0g,
    const float* __restrict__ ws, float* __restrict__ out) {
  __shared__ float sPart[8][128][20];    // GEMM2 partials [wave][p][z], padded
  __shared__ short8v sBF[8][32];         // B_obs^T E-A-frags
  __shared__ unsigned sKeys[512][4];     // per-step {k1a,k1b,k2a,k2b}
  __shared__ __align__(16) unsigned qnA[128 * 12];  // bf16 state, ping
  __shared__ __align__(16) unsigned qnB[128 * 12];  // bf16 state, pong
  __shared__ __align__(16) unsigned sEB[128 * 12];  // eps bf16 pairs
  __shared__ __align__(16) float sWV[512];          // 2log2e*(Wu@v + h)
  __shared__ __align__(16) float sXT[128];          // x_t - Obs_bias
  __shared__ __align__(16) float sXR[128];          // sXT * sRX
  __shared__ __align__(16) float sRX[128];          // 1/std_x
  __shared__ __align__(16) float sKx[16];
  __shared__ int   sIDX[128];
  __shared__ float sLLC[4][128];         // prologue partials only
  __shared__ float sLLD[128];            // per-particle ll_pz-ll_qz total
  __shared__ float sLLE[128];            // obs quad total

  const int tid  = threadIdx.x;
  const int b    = blockIdx.x;
  const int lane = tid & 63;
  const int wid  = tid >> 6;       // 0..7
  const int q    = lane >> 4;      // 0..3
  const int r16  = lane & 15;

  const short8v zero8 = {0, 0, 0, 0, 0, 0, 0, 0};
  const float4v zero4 = {0.f, 0.f, 0.f, 0.f};

  // ---------------- init staging ----------------
  if (tid < 256) {
    int xt = tid >> 5, sl2 = tid & 31, qq = sl2 >> 4, rr = sl2 & 15;
    short8v v;
#pragma unroll
    for (int i = 0; i < 8; ++i)
      v[i] = f2bf(Bobs[(size_t)(qq * 8 + i) * 128 + xt * 16 + rr]);
    sBF[xt][sl2] = v;
  }
  {  // per-step threefry keys
    int t = tid;
    unsigned kt0, kt1;
    tf2x32(0u, 42u, 0u, (unsigned)t, kt0, kt1);
    unsigned k1a = 0, k1b = 0, k2a = kt0, k2b = kt1;
    if (t > 0) {
      tf2x32(kt0, kt1, 0u, 0u, k1a, k1b);
      tf2x32(kt0, kt1, 0u, 1u, k2a, k2b);
    }
    sKeys[t][0] = k1a; sKeys[t][1] = k1b; sKeys[t][2] = k2a; sKeys[t][3] = k2b;
  }
  if (tid < 128) sRX[tid] = ws[WS_RSTDX + tid];

  // ---- persistent per-lane register fragments ----
  short8v a1f[4];
#pragma unroll
  for (int j = 0; j < 4; ++j) {
    short8v v = {0, 0, 0, 0, 0, 0, 0, 0};
    const float* src = ng + (size_t)((wid + 8 * j) * 16 + r16) * 16 + 4 * q;
#pragma unroll
    for (int i = 0; i < 4; ++i) v[i] = f2bf(TWO_LOG2E * src[i]);
    a1f[j] = v;
  }
  short8v a2f[2];
#pragma unroll
  for (int P = 0; P < 2; ++P) {
    short8v v;
#pragma unroll
    for (int i = 0; i < 4; ++i) {
      v[i]     = f2bf(mg[(size_t)((wid + 16 * P) * 16 + 4 * q + i) * 16 + r16]);
      v[4 + i] = f2bf(mg[(size_t)((wid + 16 * P + 8) * 16 + 4 * q + i) * 16 + r16]);
    }
    a2f[P] = v;
  }
  short8v aD;
  {
    const float* adsrc = (q < 2) ? (ws + WS_OMA + 256) : (ws + WS_L + 256);
    const int kb = (q & 1) * 8;
#pragma unroll
    for (int i = 0; i < 8; ++i)
      aD[i] = f2bf(adsrc[r16 * 16 + kb + i]);
  }
  float rsz4[4];
#pragma unroll
  for (int i = 0; i < 4; ++i) rsz4[i] = ws[WS_RSTDZ + 16 + 4 * q + i];

  const float cobs = ws[WS_CONST + 0];
  const float cc0  = ws[WS_CONST + 1];
  const float cc1  = ws[WS_CONST + 2];
  __syncthreads();

  float elbo = 0.0f;
  short* eb16 = (short*)sEB;         // [p][s]: index p*24 + s
  const int p    = wid * 16 + r16;   // this lane's particle in D/E
  const int srcA = 32 * q + r16;     // D/E fragment-assembly sources (q<2)
  const int srcB = srcA + 16;
  const int sl   = q * 16 + r16;

  // ======================= t = 0 prologue ==================================
  {
    if (wid == 1) {
#pragma unroll
      for (int h2 = 0; h2 < 2; ++h2) {
        int xx = lane + 64 * h2;
        float xv = xg[((size_t)b * 128 + xx) * 512] - Obias[xx];
        sXT[xx] = xv;
        sXR[xx] = xv * sRX[xx];
      }
    }
    {  // RNG t=0: both outputs per hash (2 normals/call), 2 calls/thread
      unsigned k2a = sKeys[0][2], k2b = sKeys[0][3];
#pragma unroll
      for (int j = 0; j < 2; ++j) {
        int c = tid + 512 * j;   // 0..1023
        unsigned o0, o1;
        tf2x32(k2a, k2b, 0u, (unsigned)(b * 2048 + c), o0, o1);
        int f0 = 2 * c, f1 = 2 * c + 1;
        eb16[(f0 & 127) * 24 + (f0 >> 7)] = f2bf(normal_from_bits(o0));
        eb16[(f1 & 127) * 24 + (f1 >> 7)] = f2bf(normal_from_bits(o1));
      }
    }
    __syncthreads();

    // ---- phase D0 (scalar, cold path) ----
    {
      const int kk = tid & 127, zg = tid >> 7;  // zg 0..3
      float ep[16];
#pragma unroll
      for (int w2 = 0; w2 < 8; ++w2) {
        unsigned uw = sEB[kk * 12 + w2];
        ep[2 * w2]     = __uint_as_float(uw << 16);
        ep[2 * w2 + 1] = __uint_as_float(uw & 0xffff0000u);
      }
      float part = 0.0f;
      if (zg == 0) {
        float qd = 0.0f;
#pragma unroll
        for (int s = 0; s < 16; ++s) qd = fmaf(ep[s], ep[s], qd);
        part = 0.5f * qd;
      }
      float v0[8];
#pragma unroll
      for (int d = 0; d < 8; ++d) v0[d] = ug[((size_t)b * 8 + d) * 512];
      float pm0[16];
#pragma unroll
      for (int s = 0; s < 16; ++s) {
        float a = b0g[s];
#pragma unroll
        for (int d = 0; d < 8; ++d) a = fmaf(W0g[s * 8 + d], v0[d], a);
        pm0[s] = a;
      }
      const float* Kg0p = ws + WS_KG;
      const float* omap = ws + WS_OMA;
      const float* Lp   = ws + WS_L;
      const float* rsz  = ws + WS_RSTDZ;
      float qnv[4];
#pragma unroll
      for (int zi = 0; zi < 4; ++zi) {
        int z = zg * 4 + zi;
        float mq = 0.0f;
        for (int xx = 0; xx < 128; ++xx)
          mq = fmaf(Kg0p[z * 128 + xx], sXT[xx], mq);
#pragma unroll
        for (int s = 0; s < 16; ++s) mq = fmaf(omap[z * 16 + s], pm0[s], mq);
        float qn = mq;
#pragma unroll
        for (int s = 0; s < 16; ++s) qn = fmaf(Lp[z * 16 + s], ep[s], qn);
        qnv[zi] = qn;
        float pz = b0g[z];
#pragma unroll
        for (int d = 0; d < 8; ++d) pz = fmaf(W0g[z * 8 + d], v0[d], pz);
        float r = (qn - pz) * rsz[z];
        part = fmaf(-0.5f * r, r, part);
      }
      qnA[kk * 12 + zg * 2 + 0] = packbf(qnv[0], qnv[1]);
      qnA[kk * 12 + zg * 2 + 1] = packbf(qnv[2], qnv[3]);
      sLLC[zg][kk] = part;
    }
    __syncthreads();

    // ---- phase E0 (+ sLLD reduction) ----
    {
      short8v bq = zero8;
      if (q < 2) bq = *(const short8v*)&qnA[p * 12 + q * 4];
      float ea = 0.0f;
#pragma unroll
      for (int xt = 0; xt < 8; ++xt) {
        short8v ab = (q < 2) ? sBF[xt][sl] : zero8;
        float4v d = MFMA32(ab, bq, zero4);
        float4v xr = *(const float4v*)&sXR[xt * 16 + q * 4];
        float4v rx = *(const float4v*)&sRX[xt * 16 + q * 4];
        float d0 = xr.x - d.x * rx.x; ea = fmaf(d0, d0, ea);
        float d1 = xr.y - d.y * rx.y; ea = fmaf(d1, d1, ea);
        float d2 = xr.z - d.z * rx.z; ea = fmaf(d2, d2, ea);
        float d3 = xr.w - d.w * rx.w; ea = fmaf(d3, d3, ea);
      }
      ea += __shfl_xor(ea, 16, 64);
      ea += __shfl_xor(ea, 32, 64);
      if (q == 0) sLLE[p] = ea;
      if (tid < 128)
        sLLD[tid] = sLLC[0][tid] + sLLC[1][tid] + sLLC[2][tid] + sLLC[3][tid];
    }
    __syncthreads();
  }

  // ======================= hot loop: t = 1..511 ============================
  for (int t = 1; t < 512; ++t) {
    const unsigned* qnPrev = (t & 1) ? qnA : qnB;
    unsigned* qnCur = (t & 1) ? qnB : qnA;

    // ===== phase FA: F(t-1)+resample (w0) | x/Kx (w1) | wv+RNG (w2-7) ======
    if (wid == 0) {
      float cc = (t == 1) ? cc0 : cc1;
      float lw0 = 0, lw1 = 0;
#pragma unroll
      for (int half = 0; half < 2; ++half) {
        int j = 2 * lane + half;
        float v = -0.5f * sLLE[j] + cobs + cc + sLLD[j];
        if (half) lw1 = v; else lw0 = v;
      }
      float mx = fmaxf(lw0, lw1);
#pragma unroll
      for (int d = 32; d >= 1; d >>= 1) mx = fmaxf(mx, __shfl_xor(mx, d, 64));
      float ea = __expf(lw0 - mx), eb = __expf(lw1 - mx);
      float se = ea + eb;
#pragma unroll
      for (int d = 32; d >= 1; d >>= 1) se += __shfl_xor(se, d, 64);
      elbo += logf(se) + mx - 4.85203026f;  // log(128)

      float run = ea + eb;
#pragma unroll
      for (int d = 1; d < 64; d <<= 1) {
        float v = __shfl_up(run, (unsigned)d, 64);
        if (lane >= d) run += v;
      }
      float tot = __shfl(run, 63, 64);
      float inv = 1.0f / tot;
      float c0 = (run - eb) * inv;
      float c1 = run * inv;
      unsigned o0, o1;
      tf2x32(sKeys[t][0], sKeys[t][1], 0u, (unsigned)b, o0, o1);
      unsigned bits = o0 ^ o1;
      float u0 = __uint_as_float((bits >> 9) | 0x3f800000u) - 1.0f;
      int S0, S1;
      {
        int s = (int)fmaf(c0, 128.0f, -u0);
        s = (s < 0) ? 0 : ((s > 128) ? 128 : s);
        while (s > 0   && (u0 + (float)(s - 1)) * 0.0078125f >  c0) --s;
        while (s < 128 && (u0 + (float)s)       * 0.0078125f <= c0) ++s;
        S0 = s;
        s = (int)fmaf(c1, 128.0f, -u0);
        s = (s < 0) ? 0 : ((s > 128) ? 128 : s);
        while (s > 0   && (u0 + (float)(s - 1)) * 0.0078125f >  c1) --s;
        while (s < 128 && (u0 + (float)s)       * 0.0078125f <= c1) ++s;
        S1 = s;
      }
      if (lane == 63) S1 = 128;
      int Sp = __shfl_up(S1, 1, 64);
      if (lane == 0) Sp = 0;
      if (S0 > S1) S0 = S1;
      if (Sp > S0) Sp = S0;
      for (int j = Sp; j < S0; ++j) sIDX[j] = 2 * lane;
      for (int j = S0; j < S1; ++j) sIDX[j] = 2 * lane + 1;
    } else if (wid == 1) {
#pragma unroll
      for (int h2 = 0; h2 < 2; ++h2) {
        int xx = lane + 64 * h2;
        float xv = xg[((size_t)b * 128 + xx) * 512 + t] - Obias[xx];
        sXT[xx] = xv;
        sXR[xx] = xv * sRX[xx];
      }
      int z = lane >> 2, xq = lane & 3;
      const float* Kgp = ws + WS_KG + 2048 + z * 128;
      float a = 0.0f;
      for (int jj = 0; jj < 32; ++jj) {
        int xx = xq + 4 * jj;
        a = fmaf(Kgp[xx], sXT[xx], a);
      }
      a += __shfl_xor(a, 1, 64);
      a += __shfl_xor(a, 2, 64);
      if (xq == 0) sKx[z] = a;
    } else {
      if (wid == 2) {  // wv stage (pre-scaled by 2*log2e)
        float v[8];
#pragma unroll
        for (int d = 0; d < 8; ++d) v[d] = ug[((size_t)b * 8 + d) * 512 + (t - 1)];
#pragma unroll
        for (int qq = 0; qq < 8; ++qq) {
          int N = lane + 64 * qq;
          const float4* wr = (const float4*)&Wug[N * 8];
          float4 wa = wr[0], wb = wr[1];
          float a = hg[N];
          a = fmaf(wa.x, v[0], a); a = fmaf(wa.y, v[1], a);
          a = fmaf(wa.z, v[2], a); a = fmaf(wa.w, v[3], a);
          a = fmaf(wb.x, v[4], a); a = fmaf(wb.y, v[5], a);
          a = fmaf(wb.z, v[6], a); a = fmaf(wb.w, v[7], a);
          sWV[N] = TWO_LOG2E * a;
        }
      }
      // RNG(t): both outputs per hash; waves 2..7 (384 lanes), 1024 calls
      unsigned k2a = sKeys[t][2], k2b = sKeys[t][3];
      int lt = tid - 128;  // 0..383
      for (int c = lt; c < 1024; c += 384) {
        unsigned o0, o1;
        tf2x32(k2a, k2b, 0u, (unsigned)(b * 2048 + c), o0, o1);
        int f0 = 2 * c, f1 = 2 * c + 1;
        eb16[(f0 & 127) * 24 + (f0 >> 7)] = f2bf(normal_from_bits(o0));
        eb16[(f1 & 127) * 24 + (f1 >> 7)] = f2bf(normal_from_bits(o1));
      }
    }
    __syncthreads();

    // ===== phase C: kt-sliced transition (prefetched state, no shuffles) ===
    {
      float4v cin[4];
#pragma unroll
      for (int j = 0; j < 4; ++j)
        cin[j] = *(const float4v*)&sWV[(wid + 8 * j) * 16 + 4 * q];
      // prefetch all 8 resample indices + state words (overlap LDS latency)
      uint2 zw8[8];
#pragma unroll
      for (int pt = 0; pt < 8; ++pt) {
        int idxp = sIDX[pt * 16 + r16];
        zw8[pt] = *(const uint2*)&qnPrev[idxp * 12 + 2 * q];
      }
#pragma unroll
      for (int pt = 0; pt < 8; ++pt) {
        const int pp = pt * 16 + r16;
        short8v bz = mk8(zw8[pt].x, zw8[pt].y, 0u, 0u);
        float4v d1a = MFMA32(a1f[0], bz, cin[0]);
        float4v d1b = MFMA32(a1f[1], bz, cin[1]);
        float4v d1c = MFMA32(a1f[2], bz, cin[2]);
        float4v d1d = MFMA32(a1f[3], bz, cin[3]);
        unsigned pa0 = cvtpk(tanh_fast2e(d1a.x), tanh_fast2e(d1a.y));
        unsigned pa1 = cvtpk(tanh_fast2e(d1a.z), tanh_fast2e(d1a.w));
        unsigned pb0 = cvtpk(tanh_fast2e(d1b.x), tanh_fast2e(d1b.y));
        unsigned pb1 = cvtpk(tanh_fast2e(d1b.z), tanh_fast2e(d1b.w));
        unsigned pc0 = cvtpk(tanh_fast2e(d1c.x), tanh_fast2e(d1c.y));
        unsigned pc1 = cvtpk(tanh_fast2e(d1c.z), tanh_fast2e(d1c.w));
        unsigned pd0 = cvtpk(tanh_fast2e(d1d.x), tanh_fast2e(d1d.y));
        unsigned pd1 = cvtpk(tanh_fast2e(d1d.z), tanh_fast2e(d1d.w));
        float4v a8 = MFMA32(a2f[0], mk8(pa0, pa1, pb0, pb1), zero4);
        a8 = MFMA32(a2f[1], mk8(pc0, pc1, pd0, pd1), a8);
        *(float4v*)&sPart[wid][pp][4 * q] = a8;
      }
    }
    __syncthreads();

    // ===== phase DE: reduce + proposal MFMA + obs MFMA =====================
    {
      float4v red = zero4;
#pragma unroll
      for (int wv = 0; wv < 8; ++wv)
        red += *(const float4v*)&sPart[wv][p][4 * q];
      const int idxp = sIDX[p];
      uint2 zw = *(const uint2*)&qnPrev[idxp * 12 + 2 * q];
      float zl0 = __uint_as_float(zw.x << 16);
      float zl1 = __uint_as_float(zw.x & 0xffff0000u);
      float zl2 = __uint_as_float(zw.y << 16);
      float zl3 = __uint_as_float(zw.y & 0xffff0000u);
      float pm0 = fmaf(0.1f, red.x, 0.9f * zl0);
      float pm1 = fmaf(0.1f, red.y, 0.9f * zl1);
      float pm2 = fmaf(0.1f, red.z, 0.9f * zl2);
      float pm3 = fmaf(0.1f, red.w, 0.9f * zl3);

      unsigned w01 = cvtpk(pm0, pm1), w23 = cvtpk(pm2, pm3);
      unsigned bA0 = (unsigned)__shfl((int)w01, srcA, 64);
      unsigned bA1 = (unsigned)__shfl((int)w23, srcA, 64);
      unsigned bB0 = (unsigned)__shfl((int)w01, srcB, 64);
      unsigned bB1 = (unsigned)__shfl((int)w23, srcB, 64);
      short8v bw;
      if (q < 2) {
        uint4v uu = {bA0, bA1, bB0, bB1};
        bw = __builtin_bit_cast(short8v, uu);
      } else {
        bw = *(const short8v*)&sEB[p * 12 + (q - 2) * 4];
      }
      float4v cinD = *(const float4v*)&sKx[4 * q];
      float4v aq = MFMA32(aD, bw, cinD);
      float part = 0.0f;
      if (q >= 2) {
        uint4v uw = __builtin_bit_cast(uint4v, bw);
        float e0 = __uint_as_float(uw.x << 16);
        float e1 = __uint_as_float(uw.x & 0xffff0000u);
        float e2 = __uint_as_float(uw.y << 16);
        float e3 = __uint_as_float(uw.y & 0xffff0000u);
        float e4 = __uint_as_float(uw.z << 16);
        float e5 = __uint_as_float(uw.z & 0xffff0000u);
        float e6 = __uint_as_float(uw.w << 16);
        float e7 = __uint_as_float(uw.w & 0xffff0000u);
        float s2 = 0.0f;
        s2 = fmaf(e0, e0, s2); s2 = fmaf(e1, e1, s2);
        s2 = fmaf(e2, e2, s2); s2 = fmaf(e3, e3, s2);
        s2 = fmaf(e4, e4, s2); s2 = fmaf(e5, e5, s2);
        s2 = fmaf(e6, e6, s2); s2 = fmaf(e7, e7, s2);
        part = 0.5f * s2;
      }
      float r0 = (aq.x - pm0) * rsz4[0];
      float r1 = (aq.y - pm1) * rsz4[1];
      float r2 = (aq.z - pm2) * rsz4[2];
      float r3 = (aq.w - pm3) * rsz4[3];
      part = fmaf(-0.5f * r0, r0, part);
      part = fmaf(-0.5f * r1, r1, part);
      part = fmaf(-0.5f * r2, r2, part);
      part = fmaf(-0.5f * r3, r3, part);
      unsigned y01 = cvtpk(aq.x, aq.y), y23 = cvtpk(aq.z, aq.w);
      *(uint2*)&qnCur[p * 12 + 2 * q] = make_uint2(y01, y23);
      part += __shfl_xor(part, 16, 64);
      part += __shfl_xor(part, 32, 64);
      if (q == 0) sLLD[p] = part;

      unsigned qA0 = (unsigned)__shfl((int)y01, srcA, 64);
      unsigned qA1 = (unsigned)__shfl((int)y23, srcA, 64);
      unsigned qB0 = (unsigned)__shfl((int)y01, srcB, 64);
      unsigned qB1 = (unsigned)__shfl((int)y23, srcB, 64);
      short8v bq = zero8;
      if (q < 2) {
        uint4v uu = {qA0, qA1, qB0, qB1};
        bq = __builtin_bit_cast(short8v, uu);
      }
      float ea = 0.0f;
#pragma unroll
      for (int xt = 0; xt < 8; ++xt) {
        short8v ab = (q < 2) ? sBF[xt][sl] : zero8;
        float4v d = MFMA32(ab, bq, zero4);
        float4v xr = *(const float4v*)&sXR[xt * 16 + q * 4];
        float4v rx = *(const float4v*)&sRX[xt * 16 + q * 4];
        float d0 = xr.x - d.x * rx.x; ea = fmaf(d0, d0, ea);
        float d1 = xr.y - d.y * rx.y; ea = fmaf(d1, d1, ea);
        float d2 = xr.z - d.z * rx.z; ea = fmaf(d2, d2, ea);
        float d3 = xr.w - d.w * rx.w; ea = fmaf(d3, d3, ea);
      }
      ea += __shfl_xor(ea, 16, 64);
      ea += __shfl_xor(ea, 32, 64);
      if (q == 0) sLLE[p] = ea;
    }
    __syncthreads();
  }

  // ===== final F(511): elbo contribution only ==============================
  if (wid == 0) {
    float lw0 = 0, lw1 = 0;
#pragma unroll
    for (int half = 0; half < 2; ++half) {
      int j = 2 * lane + half;
      float v = -0.5f * sLLE[j] + cobs + cc1 + sLLD[j];
      if (half) lw1 = v; else lw0 = v;
    }
    float mx = fmaxf(lw0, lw1);
#pragma unroll
    for (int d = 32; d >= 1; d >>= 1) mx = fmaxf(mx, __shfl_xor(mx, d, 64));
    float se = __expf(lw0 - mx) + __expf(lw1 - mx);
#pragma unroll
    for (int d = 32; d >= 1; d >>= 1) se += __shfl_xor(se, d, 64);
    elbo += logf(se) + mx - 4.85203026f;
  }
  if (tid == 0) out[b] = -elbo * (1.0f / 512.0f);
}

extern "C" void kernel_launch(void* const* d_in, const int* in_sizes, int n_in,
                              void* d_out, int out_size, void* d_ws, size_t ws_size,
                              hipStream_t stream) {
  const float* x     = (const float*)d_in[0];
  const float* u     = (const float*)d_in[1];
  const float* R_z   = (const float*)d_in[2];
  const float* R_z0  = (const float*)d_in[3];
  const float* R_x   = (const float*)d_in[4];
  const float* B_obs = (const float*)d_in[5];
  const float* Obias = (const float*)d_in[6];
  const float* m     = (const float*)d_in[7];
  const float* n     = (const float*)d_in[8];
  const float* Wu    = (const float*)d_in[9];
  const float* h     = (const float*)d_in[10];
  const float* W0    = (const float*)d_in[11];
  const float* b0    = (const float*)d_in[12];
  float* ws = (float*)d_ws;
  float* outp = (float*)d_out;

  precomp_kernel<<<dim3(1), dim3(256), 0, stream>>>(R_z, R_z0, R_x, B_obs, ws);
  pf_kernel<<<dim3(128), dim3(512), 0, stream>>>(x, u, B_obs, Obias, m, n, Wu, h,
                                                 W0, b0, ws, outp);
}

// Round 19
// 4614.141 us; speedup vs baseline: 1.3730x; 1.2347x over previous
//
#include <hip/hip_runtime.h>
#include <hip/hip_bf16.h>

// Particle-filter VAE ELBO, MI355X single-fused-kernel implementation.
// Round 19: r18 with ONE fix: tanh uses raw v_exp_f32 via inline asm
// (r18's exp2f() was the PRECISE libm exp2 -> multi-instruction expansion,
// regressing 4.55->5.43ms; the fast path is the bare hardware instruction,
// same class as the v_rcp_f32 builtin already in use).
// Structure = r16 (PASS, 4.55ms) + n/wv pre-scaled by 2*log2(e).

#define WS_KG    0
#define WS_OMA   4096
#define WS_L     4608
#define WS_RSTDZ 5120
#define WS_RSTDX 5152
#define WS_CONST 5280

#define LOG2PI_F 1.8378770664093453f
#define TWO_LOG2E 2.8853900817779268f

typedef __attribute__((ext_vector_type(8))) short short8v;
typedef __attribute__((ext_vector_type(4))) float float4v;
typedef __attribute__((ext_vector_type(4))) unsigned uint4v;

#define MFMA32(a, b, c) \
  __builtin_amdgcn_mfma_f32_16x16x32_bf16((a), (b), (c), 0, 0, 0)

__device__ __forceinline__ unsigned rotl32(unsigned v, int r) {
  return (v << r) | (v >> (32 - r));
}

// Threefry-2x32, 20 rounds.
__device__ __forceinline__ void tf2x32(unsigned k0, unsigned k1,
                                       unsigned c0, unsigned c1,
                                       unsigned& o0, unsigned& o1) {
  unsigned ks2 = k0 ^ k1 ^ 0x1BD11BDAu;
  unsigned x0 = c0 + k0, x1 = c1 + k1;
#define TF_R4(ra, rb, rc, rd) \
  x0 += x1; x1 = rotl32(x1, ra); x1 ^= x0; \
  x0 += x1; x1 = rotl32(x1, rb); x1 ^= x0; \
  x0 += x1; x1 = rotl32(x1, rc); x1 ^= x0; \
  x0 += x1; x1 = rotl32(x1, rd); x1 ^= x0;
  TF_R4(13, 15, 26, 6)  x0 += k1;  x1 += ks2 + 1u;
  TF_R4(17, 29, 16, 24) x0 += ks2; x1 += k0 + 2u;
  TF_R4(13, 15, 26, 6)  x0 += k0;  x1 += k1 + 3u;
  TF_R4(17, 29, 16, 24) x0 += k1;  x1 += ks2 + 4u;
  TF_R4(13, 15, 26, 6)  x0 += ks2; x1 += k0 + 5u;
#undef TF_R4
  o0 = x0; o1 = x1;
}

// XLA ErfInv32 polynomial (Giles).
__device__ __forceinline__ float erfinv_f(float x) {
  float w = -log1pf(-x * x);
  float p;
  if (w < 5.0f) {
    w -= 2.5f;
    p = 2.81022636e-08f;
    p = fmaf(p, w, 3.43273939e-07f);
    p = fmaf(p, w, -3.5233877e-06f);
    p = fmaf(p, w, -4.39150654e-06f);
    p = fmaf(p, w, 0.00021858087f);
    p = fmaf(p, w, -0.00125372503f);
    p = fmaf(p, w, -0.00417768164f);
    p = fmaf(p, w, 0.246640727f);
    p = fmaf(p, w, 1.50140941f);
  } else {
    w = sqrtf(w) - 3.0f;
    p = -0.000200214257f;
    p = fmaf(p, w, 0.000100950558f);
    p = fmaf(p, w, 0.00134934322f);
    p = fmaf(p, w, -0.00367342844f);
    p = fmaf(p, w, 0.00573950773f);
    p = fmaf(p, w, -0.0076224613f);
    p = fmaf(p, w, 0.00943887047f);
    p = fmaf(p, w, 1.00167406f);
    p = fmaf(p, w, 2.83297682f);
  }
  return p * x;
}

__device__ __forceinline__ float normal_from_bits(unsigned bits) {
  float f = __uint_as_float((bits >> 9) | 0x3f800000u) - 1.0f;  // [0,1)
  const float lo = -0.99999994f;
  float uu = fmaxf(lo, fmaf(f, 2.0f, lo));
  return 1.41421354f * erfinv_f(uu);
}

// raw hardware 2^x (single v_exp_f32, no libm fix-ups)
__device__ __forceinline__ float exp2_raw(float d) {
  float r;
  asm("v_exp_f32 %0, %1" : "=v"(r) : "v"(d));
  return r;
}

// input pre-scaled by 2*log2(e): tanh(x) with d = 2x*log2(e) -> 2^d = e^{2x}
__device__ __forceinline__ float tanh_fast2e(float d) {
  float e = exp2_raw(d);
  return 1.0f - 2.0f * __builtin_amdgcn_rcpf(e + 1.0f);
}

// f32 -> bf16 bits, round-to-nearest-even (cold paths).
__device__ __forceinline__ short f2bf(float f) {
  unsigned u = __float_as_uint(f);
  unsigned r = (u + 0x7fffu + ((u >> 16) & 1u)) >> 16;
  return (short)r;
}

__device__ __forceinline__ unsigned packbf(float a, float b) {
  return (unsigned)(unsigned short)f2bf(a) |
         ((unsigned)(unsigned short)f2bf(b) << 16);
}

// hot pack: single HW instruction, RNE.
__device__ __forceinline__ unsigned cvtpk(float a, float b) {
  unsigned r;
  asm("v_cvt_pk_bf16_f32 %0, %1, %2" : "=v"(r) : "v"(a), "v"(b));
  return r;
}

__device__ __forceinline__ short8v mk8(unsigned a, unsigned b,
                                       unsigned c, unsigned d) {
  uint4v u = {a, b, c, d};
  return __builtin_bit_cast(short8v, u);
}

// ---------------- precompute kernel: Kalman quantities into ws --------------
__global__ void precomp_kernel(const float* __restrict__ Rz,
                               const float* __restrict__ Rz0,
                               const float* __restrict__ Rx,
                               const float* __restrict__ Bobs,
                               float* __restrict__ ws) {
  __shared__ float svarx[128];
  __shared__ float svarz[16];
  __shared__ float sprec[16][16];
  __shared__ float saug[16][32];
  __shared__ float svq[16][16];
  __shared__ float sLm[16][16];
  __shared__ float skg[16][128];
  const int tid = threadIdx.x;  // 256 threads

  if (tid < 128) {
    float r = Rx[tid];
    svarx[tid] = fmaxf(r * r, 1e-8f);
    ws[WS_RSTDX + tid] = 1.0f / fmaxf(fabsf(r), 1e-4f);
  }
  if (tid == 0) {
    float a = 0.0f;
    for (int xx = 0; xx < 128; ++xx) a += logf(fmaxf(fabsf(Rx[xx]), 1e-4f));
    ws[WS_CONST + 0] = -a - 0.5f * 128.0f * LOG2PI_F;
  }
  __syncthreads();

  for (int set = 0; set < 2; ++set) {
    const float* Rzp = (set == 0) ? Rz0 : Rz;
    if (tid < 16) {
      float v = Rzp[tid] * Rzp[tid] + 1e-8f;
      svarz[tid] = v;
      ws[WS_RSTDZ + set * 16 + tid] = 1.0f / sqrtf(v);
    }
    __syncthreads();
    {
      int z1 = tid >> 4, z2 = tid & 15;
      float a = 0.0f;
      for (int xx = 0; xx < 128; ++xx)
        a += Bobs[z1 * 128 + xx] * Bobs[z2 * 128 + xx] / svarx[xx];
      if (z1 == z2) a += 1.0f / svarz[z1];
      sprec[z1][z2] = a;
    }
    __syncthreads();
    if (tid == 0) {
      for (int r = 0; r < 16; ++r)
        for (int c2 = 0; c2 < 32; ++c2)
          saug[r][c2] = (c2 < 16) ? sprec[r][c2] : ((c2 - 16 == r) ? 1.0f : 0.0f);
      for (int p = 0; p < 16; ++p) {
        float ip = 1.0f / saug[p][p];
        for (int c2 = 0; c2 < 32; ++c2) saug[p][c2] *= ip;
        for (int r = 0; r < 16; ++r) if (r != p) {
          float f = saug[r][p];
          for (int c2 = 0; c2 < 32; ++c2) saug[r][c2] -= f * saug[p][c2];
        }
      }
      for (int r = 0; r < 16; ++r)
        for (int c2 = 0; c2 < 16; ++c2)
          svq[r][c2] = 0.5f * (saug[r][16 + c2] + saug[c2][16 + r]) +
                       ((r == c2) ? 1e-8f : 0.0f);
      for (int j = 0; j < 16; ++j) {
        float d = svq[j][j];
        for (int s = 0; s < j; ++s) d -= sLm[j][s] * sLm[j][s];
        float dj = sqrtf(d);
        sLm[j][j] = dj;
        for (int r = j + 1; r < 16; ++r) {
          float a = svq[r][j];
          for (int s = 0; s < j; ++s) a -= sLm[r][s] * sLm[j][s];
          sLm[r][j] = a / dj;
        }
        for (int r = 0; r < j; ++r) sLm[r][j] = 0.0f;
      }
      float cc = 0.0f;
      for (int j = 0; j < 16; ++j) cc += logf(sLm[j][j]) - logf(sqrtf(svarz[j]));
      ws[WS_CONST + 1 + set] = cc;
      for (int r = 0; r < 16; ++r)
        for (int c2 = 0; c2 < 16; ++c2)
          ws[WS_L + set * 256 + r * 16 + c2] = sLm[r][c2];
    }
    __syncthreads();
    for (int o = tid; o < 2048; o += 256) {
      int z = o >> 7, xx = o & 127;
      float a = 0.0f;
      for (int s = 0; s < 16; ++s) a += saug[z][16 + s] * Bobs[s * 128 + xx];
      a /= svarx[xx];
      skg[z][xx] = a;
      ws[WS_KG + set * 2048 + o] = a;
    }
    __syncthreads();
    {
      int z = tid >> 4, s = tid & 15;
      float a = 0.0f;
      for (int xx = 0; xx < 128; ++xx) a += skg[z][xx] * Bobs[s * 128 + xx];
      ws[WS_OMA + set * 256 + tid] = ((z == s) ? 1.0f : 0.0f) - a;
    }
    __syncthreads();
  }
}

// ---------------- main particle-filter kernel: 1 block = 1 batch -----------
__global__ __launch_bounds__(512, 1) void pf_kernel(
    const float* __restrict__ xg, const float* __restrict__ ug,
    const float* __restrict__ Bobs, const float* __restrict__ Obias,
    const float* __restrict__ mg, const float* __restrict__ ng,
    const float* __restrict__ Wug, const float* __restrict__ hg,
    const float* __restrict__ W0g, const float* __restrict__ b0g,
    const float* __restrict__ ws, float* __restrict__ out) {
  __shared__ float sPart[8][128][20];    // GEMM2 partials [wave][p][z], padded
  __shared__ short8v sBF[8][32];         // B_obs^T E-A-frags
  __shared__ unsigned sKeys[512][4];     // per-step {k1a,k1b,k2a,k2b}
  __shared__ __align__(16) unsigned qnA[128 * 12];  // bf16 state, ping
  __shared__ __align__(16) unsigned qnB[128 * 12];  // bf16 state, pong
  __shared__ __align__(16) unsigned sEB[128 * 12];  // eps bf16 pairs
  __shared__ __align__(16) float sWV[512];          // 2log2e*(Wu@v + h)
  __shared__ __align__(16) float sXT[128];          // x_t - Obs_bias
  __shared__ __align__(16) float sXR[128];          // sXT * sRX
  __shared__ __align__(16) float sRX[128];          // 1/std_x
  __shared__ __align__(16) float sKx[16];
  __shared__ int   sIDX[128];
  __shared__ float sLLC[4][128];         // prologue partials only
  __shared__ float sLLD[128];            // per-particle ll_pz-ll_qz total
  __shared__ float sLLE[128];            // obs quad total

  const int tid  = threadIdx.x;
  const int b    = blockIdx.x;
  const int lane = tid & 63;
  const int wid  = tid >> 6;       // 0..7
  const int q    = lane >> 4;      // 0..3
  const int r16  = lane & 15;

  const short8v zero8 = {0, 0, 0, 0, 0, 0, 0, 0};
  const float4v zero4 = {0.f, 0.f, 0.f, 0.f};

  // ---------------- init staging ----------------
  if (tid < 256) {
    int xt = tid >> 5, sl2 = tid & 31, qq = sl2 >> 4, rr = sl2 & 15;
    short8v v;
#pragma unroll
    for (int i = 0; i < 8; ++i)
      v[i] = f2bf(Bobs[(size_t)(qq * 8 + i) * 128 + xt * 16 + rr]);
    sBF[xt][sl2] = v;
  }
  {  // per-step threefry keys
    int t = tid;
    unsigned kt0, kt1;
    tf2x32(0u, 42u, 0u, (unsigned)t, kt0, kt1);
    unsigned k1a = 0, k1b = 0, k2a = kt0, k2b = kt1;
    if (t > 0) {
      tf2x32(kt0, kt1, 0u, 0u, k1a, k1b);
      tf2x32(kt0, kt1, 0u, 1u, k2a, k2b);
    }
    sKeys[t][0] = k1a; sKeys[t][1] = k1b; sKeys[t][2] = k2a; sKeys[t][3] = k2b;
  }
  if (tid < 128) sRX[tid] = ws[WS_RSTDX + tid];

  // ---- persistent per-lane register fragments ----
  short8v a1f[4];
#pragma unroll
  for (int j = 0; j < 4; ++j) {
    short8v v = {0, 0, 0, 0, 0, 0, 0, 0};
    const float* src = ng + (size_t)((wid + 8 * j) * 16 + r16) * 16 + 4 * q;
#pragma unroll
    for (int i = 0; i < 4; ++i) v[i] = f2bf(TWO_LOG2E * src[i]);
    a1f[j] = v;
  }
  short8v a2f[2];
#pragma unroll
  for (int P = 0; P < 2; ++P) {
    short8v v;
#pragma unroll
    for (int i = 0; i < 4; ++i) {
      v[i]     = f2bf(mg[(size_t)((wid + 16 * P) * 16 + 4 * q + i) * 16 + r16]);
      v[4 + i] = f2bf(mg[(size_t)((wid + 16 * P + 8) * 16 + 4 * q + i) * 16 + r16]);
    }
    a2f[P] = v;
  }
  short8v aD;
  {
    const float* adsrc = (q < 2) ? (ws + WS_OMA + 256) : (ws + WS_L + 256);
    const int kb = (q & 1) * 8;
#pragma unroll
    for (int i = 0; i < 8; ++i)
      aD[i] = f2bf(adsrc[r16 * 16 + kb + i]);
  }
  float rsz4[4];
#pragma unroll
  for (int i = 0; i < 4; ++i) rsz4[i] = ws[WS_RSTDZ + 16 + 4 * q + i];

  const float cobs = ws[WS_CONST + 0];
  const float cc0  = ws[WS_CONST + 1];
  const float cc1  = ws[WS_CONST + 2];
  __syncthreads();

  float elbo = 0.0f;
  short* eb16 = (short*)sEB;         // [p][s]: index p*24 + s
  const int p    = wid * 16 + r16;   // this lane's particle in D/E
  const int srcA = 32 * q + r16;     // D/E fragment-assembly sources (q<2)
  const int srcB = srcA + 16;
  const int sl   = q * 16 + r16;

  // ======================= t = 0 prologue ==================================
  {
    if (wid == 1) {
#pragma unroll
      for (int h2 = 0; h2 < 2; ++h2) {
        int xx = lane + 64 * h2;
        float xv = xg[((size_t)b * 128 + xx) * 512] - Obias[xx];
        sXT[xx] = xv;
        sXR[xx] = xv * sRX[xx];
      }
    }
    {  // RNG t=0: both outputs per hash (2 normals/call), 2 calls/thread
      unsigned k2a = sKeys[0][2], k2b = sKeys[0][3];
#pragma unroll
      for (int j = 0; j < 2; ++j) {
        int c = tid + 512 * j;   // 0..1023
        unsigned o0, o1;
        tf2x32(k2a, k2b, 0u, (unsigned)(b * 2048 + c), o0, o1);
        int f0 = 2 * c, f1 = 2 * c + 1;
        eb16[(f0 & 127) * 24 + (f0 >> 7)] = f2bf(normal_from_bits(o0));
        eb16[(f1 & 127) * 24 + (f1 >> 7)] = f2bf(normal_from_bits(o1));
      }
    }
    __syncthreads();

    // ---- phase D0 (scalar, cold path) ----
    {
      const int kk = tid & 127, zg = tid >> 7;  // zg 0..3
      float ep[16];
#pragma unroll
      for (int w2 = 0; w2 < 8; ++w2) {
        unsigned uw = sEB[kk * 12 + w2];
        ep[2 * w2]     = __uint_as_float(uw << 16);
        ep[2 * w2 + 1] = __uint_as_float(uw & 0xffff0000u);
      }
      float part = 0.0f;
      if (zg == 0) {
        float qd = 0.0f;
#pragma unroll
        for (int s = 0; s < 16; ++s) qd = fmaf(ep[s], ep[s], qd);
        part = 0.5f * qd;
      }
      float v0[8];
#pragma unroll
      for (int d = 0; d < 8; ++d) v0[d] = ug[((size_t)b * 8 + d) * 512];
      float pm0[16];
#pragma unroll
      for (int s = 0; s < 16; ++s) {
        float a = b0g[s];
#pragma unroll
        for (int d = 0; d < 8; ++d) a = fmaf(W0g[s * 8 + d], v0[d], a);
        pm0[s] = a;
      }
      const float* Kg0p = ws + WS_KG;
      const float* omap = ws + WS_OMA;
      const float* Lp   = ws + WS_L;
      const float* rsz  = ws + WS_RSTDZ;
      float qnv[4];
#pragma unroll
      for (int zi = 0; zi < 4; ++zi) {
        int z = zg * 4 + zi;
        float mq = 0.0f;
        for (int xx = 0; xx < 128; ++xx)
          mq = fmaf(Kg0p[z * 128 + xx], sXT[xx], mq);
#pragma unroll
        for (int s = 0; s < 16; ++s) mq = fmaf(omap[z * 16 + s], pm0[s], mq);
        float qn = mq;
#pragma unroll
        for (int s = 0; s < 16; ++s) qn = fmaf(Lp[z * 16 + s], ep[s], qn);
        qnv[zi] = qn;
        float pz = b0g[z];
#pragma unroll
        for (int d = 0; d < 8; ++d) pz = fmaf(W0g[z * 8 + d], v0[d], pz);
        float r = (qn - pz) * rsz[z];
        part = fmaf(-0.5f * r, r, part);
      }
      qnA[kk * 12 + zg * 2 + 0] = packbf(qnv[0], qnv[1]);
      qnA[kk * 12 + zg * 2 + 1] = packbf(qnv[2], qnv[3]);
      sLLC[zg][kk] = part;
    }
    __syncthreads();

    // ---- phase E0 (+ sLLD reduction) ----
    {
      short8v bq = zero8;
      if (q < 2) bq = *(const short8v*)&qnA[p * 12 + q * 4];
      float ea = 0.0f;
#pragma unroll
      for (int xt = 0; xt < 8; ++xt) {
        short8v ab = (q < 2) ? sBF[xt][sl] : zero8;
        float4v d = MFMA32(ab, bq, zero4);
        float4v xr = *(const float4v*)&sXR[xt * 16 + q * 4];
        float4v rx = *(const float4v*)&sRX[xt * 16 + q * 4];
        float d0 = xr.x - d.x * rx.x; ea = fmaf(d0, d0, ea);
        float d1 = xr.y - d.y * rx.y; ea = fmaf(d1, d1, ea);
        float d2 = xr.z - d.z * rx.z; ea = fmaf(d2, d2, ea);
        float d3 = xr.w - d.w * rx.w; ea = fmaf(d3, d3, ea);
      }
      ea += __shfl_xor(ea, 16, 64);
      ea += __shfl_xor(ea, 32, 64);
      if (q == 0) sLLE[p] = ea;
      if (tid < 128)
        sLLD[tid] = sLLC[0][tid] + sLLC[1][tid] + sLLC[2][tid] + sLLC[3][tid];
    }
    __syncthreads();
  }

  // ======================= hot loop: t = 1..511 ============================
  for (int t = 1; t < 512; ++t) {
    const unsigned* qnPrev = (t & 1) ? qnA : qnB;
    unsigned* qnCur = (t & 1) ? qnB : qnA;

    // ===== phase FA: F(t-1)+resample (w0) | x/Kx (w1) | wv+RNG (w2-7) ======
    if (wid == 0) {
      float cc = (t == 1) ? cc0 : cc1;
      float lw0 = 0, lw1 = 0;
#pragma unroll
      for (int half = 0; half < 2; ++half) {
        int j = 2 * lane + half;
        float v = -0.5f * sLLE[j] + cobs + cc + sLLD[j];
        if (half) lw1 = v; else lw0 = v;
      }
      float mx = fmaxf(lw0, lw1);
#pragma unroll
      for (int d = 32; d >= 1; d >>= 1) mx = fmaxf(mx, __shfl_xor(mx, d, 64));
      float ea = __expf(lw0 - mx), eb = __expf(lw1 - mx);
      float se = ea + eb;
#pragma unroll
      for (int d = 32; d >= 1; d >>= 1) se += __shfl_xor(se, d, 64);
      elbo += logf(se) + mx - 4.85203026f;  // log(128)

      float run = ea + eb;
#pragma unroll
      for (int d = 1; d < 64; d <<= 1) {
        float v = __shfl_up(run, (unsigned)d, 64);
        if (lane >= d) run += v;
      }
      float tot = __shfl(run, 63, 64);
      float inv = 1.0f / tot;
      float c0 = (run - eb) * inv;
      float c1 = run * inv;
      unsigned o0, o1;
      tf2x32(sKeys[t][0], sKeys[t][1], 0u, (unsigned)b, o0, o1);
      unsigned bits = o0 ^ o1;
      float u0 = __uint_as_float((bits >> 9) | 0x3f800000u) - 1.0f;
      int S0, S1;
      {
        int s = (int)fmaf(c0, 128.0f, -u0);
        s = (s < 0) ? 0 : ((s > 128) ? 128 : s);
        while (s > 0   && (u0 + (float)(s - 1)) * 0.0078125f >  c0) --s;
        while (s < 128 && (u0 + (float)s)       * 0.0078125f <= c0) ++s;
        S0 = s;
        s = (int)fmaf(c1, 128.0f, -u0);
        s = (s < 0) ? 0 : ((s > 128) ? 128 : s);
        while (s > 0   && (u0 + (float)(s - 1)) * 0.0078125f >  c1) --s;
        while (s < 128 && (u0 + (float)s)       * 0.0078125f <= c1) ++s;
        S1 = s;
      }
      if (lane == 63) S1 = 128;
      int Sp = __shfl_up(S1, 1, 64);
      if (lane == 0) Sp = 0;
      if (S0 > S1) S0 = S1;
      if (Sp > S0) Sp = S0;
      for (int j = Sp; j < S0; ++j) sIDX[j] = 2 * lane;
      for (int j = S0; j < S1; ++j) sIDX[j] = 2 * lane + 1;
    } else if (wid == 1) {
#pragma unroll
      for (int h2 = 0; h2 < 2; ++h2) {
        int xx = lane + 64 * h2;
        float xv = xg[((size_t)b * 128 + xx) * 512 + t] - Obias[xx];
        sXT[xx] = xv;
        sXR[xx] = xv * sRX[xx];
      }
      int z = lane >> 2, xq = lane & 3;
      const float* Kgp = ws + WS_KG + 2048 + z * 128;
      float a = 0.0f;
      for (int jj = 0; jj < 32; ++jj) {
        int xx = xq + 4 * jj;
        a = fmaf(Kgp[xx], sXT[xx], a);
      }
      a += __shfl_xor(a, 1, 64);
      a += __shfl_xor(a, 2, 64);
      if (xq == 0) sKx[z] = a;
    } else {
      if (wid == 2) {  // wv stage (pre-scaled by 2*log2e)
        float v[8];
#pragma unroll
        for (int d = 0; d < 8; ++d) v[d] = ug[((size_t)b * 8 + d) * 512 + (t - 1)];
#pragma unroll
        for (int qq = 0; qq < 8; ++qq) {
          int N = lane + 64 * qq;
          const float4* wr = (const float4*)&Wug[N * 8];
          float4 wa = wr[0], wb = wr[1];
          float a = hg[N];
          a = fmaf(wa.x, v[0], a); a = fmaf(wa.y, v[1], a);
          a = fmaf(wa.z, v[2], a); a = fmaf(wa.w, v[3], a);
          a = fmaf(wb.x, v[4], a); a = fmaf(wb.y, v[5], a);
          a = fmaf(wb.z, v[6], a); a = fmaf(wb.w, v[7], a);
          sWV[N] = TWO_LOG2E * a;
        }
      }
      // RNG(t): both outputs per hash; waves 2..7 (384 lanes), 1024 calls
      unsigned k2a = sKeys[t][2], k2b = sKeys[t][3];
      int lt = tid - 128;  // 0..383
      for (int c = lt; c < 1024; c += 384) {
        unsigned o0, o1;
        tf2x32(k2a, k2b, 0u, (unsigned)(b * 2048 + c), o0, o1);
        int f0 = 2 * c, f1 = 2 * c + 1;
        eb16[(f0 & 127) * 24 + (f0 >> 7)] = f2bf(normal_from_bits(o0));
        eb16[(f1 & 127) * 24 + (f1 >> 7)] = f2bf(normal_from_bits(o1));
      }
    }
    __syncthreads();

    // ===== phase C: kt-sliced transition (prefetched state, no shuffles) ===
    {
      float4v cin[4];
#pragma unroll
      for (int j = 0; j < 4; ++j)
        cin[j] = *(const float4v*)&sWV[(wid + 8 * j) * 16 + 4 * q];
      // prefetch all 8 resample indices + state words (overlap LDS latency)
      uint2 zw8[8];
#pragma unroll
      for (int pt = 0; pt < 8; ++pt) {
        int idxp = sIDX[pt * 16 + r16];
        zw8[pt] = *(const uint2*)&qnPrev[idxp * 12 + 2 * q];
      }
#pragma unroll
      for (int pt = 0; pt < 8; ++pt) {
        const int pp = pt * 16 + r16;
        short8v bz = mk8(zw8[pt].x, zw8[pt].y, 0u, 0u);
        float4v d1a = MFMA32(a1f[0], bz, cin[0]);
        float4v d1b = MFMA32(a1f[1], bz, cin[1]);
        float4v d1c = MFMA32(a1f[2], bz, cin[2]);
        float4v d1d = MFMA32(a1f[3], bz, cin[3]);
        unsigned pa0 = cvtpk(tanh_fast2e(d1a.x), tanh_fast2e(d1a.y));
        unsigned pa1 = cvtpk(tanh_fast2e(d1a.z), tanh_fast2e(d1a.w));
        unsigned pb0 = cvtpk(tanh_fast2e(d1b.x), tanh_fast2e(d1b.y));
        unsigned pb1 = cvtpk(tanh_fast2e(d1b.z), tanh_fast2e(d1b.w));
        unsigned pc0 = cvtpk(tanh_fast2e(d1c.x), tanh_fast2e(d1c.y));
        unsigned pc1 = cvtpk(tanh_fast2e(d1c.z), tanh_fast2e(d1c.w));
        unsigned pd0 = cvtpk(tanh_fast2e(d1d.x), tanh_fast2e(d1d.y));
        unsigned pd1 = cvtpk(tanh_fast2e(d1d.z), tanh_fast2e(d1d.w));
        float4v a8 = MFMA32(a2f[0], mk8(pa0, pa1, pb0, pb1), zero4);
        a8 = MFMA32(a2f[1], mk8(pc0, pc1, pd0, pd1), a8);
        *(float4v*)&sPart[wid][pp][4 * q] = a8;
      }
    }
    __syncthreads();

    // ===== phase DE: reduce + proposal MFMA + obs MFMA =====================
    {
      float4v red = zero4;
#pragma unroll
      for (int wv = 0; wv < 8; ++wv)
        red += *(const float4v*)&sPart[wv][p][4 * q];
      const int idxp = sIDX[p];
      uint2 zw = *(const uint2*)&qnPrev[idxp * 12 + 2 * q];
      float zl0 = __uint_as_float(zw.x << 16);
      float zl1 = __uint_as_float(zw.x & 0xffff0000u);
      float zl2 = __uint_as_float(zw.y << 16);
      float zl3 = __uint_as_float(zw.y & 0xffff0000u);
      float pm0 = fmaf(0.1f, red.x, 0.9f * zl0);
      float pm1 = fmaf(0.1f, red.y, 0.9f * zl1);
      float pm2 = fmaf(0.1f, red.z, 0.9f * zl2);
      float pm3 = fmaf(0.1f, red.w, 0.9f * zl3);

      unsigned w01 = cvtpk(pm0, pm1), w23 = cvtpk(pm2, pm3);
      unsigned bA0 = (unsigned)__shfl((int)w01, srcA, 64);
      unsigned bA1 = (unsigned)__shfl((int)w23, srcA, 64);
      unsigned bB0 = (unsigned)__shfl((int)w01, srcB, 64);
      unsigned bB1 = (unsigned)__shfl((int)w23, srcB, 64);
      short8v bw;
      if (q < 2) {
        uint4v uu = {bA0, bA1, bB0, bB1};
        bw = __builtin_bit_cast(short8v, uu);
      } else {
        bw = *(const short8v*)&sEB[p * 12 + (q - 2) * 4];
      }
      float4v cinD = *(const float4v*)&sKx[4 * q];
      float4v aq = MFMA32(aD, bw, cinD);
      float part = 0.0f;
      if (q >= 2) {
        uint4v uw = __builtin_bit_cast(uint4v, bw);
        float e0 = __uint_as_float(uw.x << 16);
        float e1 = __uint_as_float(uw.x & 0xffff0000u);
        float e2 = __uint_as_float(uw.y << 16);
        float e3 = __uint_as_float(uw.y & 0xffff0000u);
        float e4 = __uint_as_float(uw.z << 16);
        float e5 = __uint_as_float(uw.z & 0xffff0000u);
        float e6 = __uint_as_float(uw.w << 16);
        float e7 = __uint_as_float(uw.w & 0xffff0000u);
        float s2 = 0.0f;
        s2 = fmaf(e0, e0, s2); s2 = fmaf(e1, e1, s2);
        s2 = fmaf(e2, e2, s2); s2 = fmaf(e3, e3, s2);
        s2 = fmaf(e4, e4, s2); s2 = fmaf(e5, e5, s2);
        s2 = fmaf(e6, e6, s2); s2 = fmaf(e7, e7, s2);
        part = 0.5f * s2;
      }
      float r0 = (aq.x - pm0) * rsz4[0];
      float r1 = (aq.y - pm1) * rsz4[1];
      float r2 = (aq.z - pm2) * rsz4[2];
      float r3 = (aq.w - pm3) * rsz4[3];
      part = fmaf(-0.5f * r0, r0, part);
      part = fmaf(-0.5f * r1, r1, part);
      part = fmaf(-0.5f * r2, r2, part);
      part = fmaf(-0.5f * r3, r3, part);
      unsigned y01 = cvtpk(aq.x, aq.y), y23 = cvtpk(aq.z, aq.w);
      *(uint2*)&qnCur[p * 12 + 2 * q] = make_uint2(y01, y23);
      part += __shfl_xor(part, 16, 64);
      part += __shfl_xor(part, 32, 64);
      if (q == 0) sLLD[p] = part;

      unsigned qA0 = (unsigned)__shfl((int)y01, srcA, 64);
      unsigned qA1 = (unsigned)__shfl((int)y23, srcA, 64);
      unsigned qB0 = (unsigned)__shfl((int)y01, srcB, 64);
      unsigned qB1 = (unsigned)__shfl((int)y23, srcB, 64);
      short8v bq = zero8;
      if (q < 2) {
        uint4v uu = {qA0, qA1, qB0, qB1};
        bq = __builtin_bit_cast(short8v, uu);
      }
      float ea = 0.0f;
#pragma unroll
      for (int xt = 0; xt < 8; ++xt) {
        short8v ab = (q < 2) ? sBF[xt][sl] : zero8;
        float4v d = MFMA32(ab, bq, zero4);
        float4v xr = *(const float4v*)&sXR[xt * 16 + q * 4];
        float4v rx = *(const float4v*)&sRX[xt * 16 + q * 4];
        float d0 = xr.x - d.x * rx.x; ea = fmaf(d0, d0, ea);
        float d1 = xr.y - d.y * rx.y; ea = fmaf(d1, d1, ea);
        float d2 = xr.z - d.z * rx.z; ea = fmaf(d2, d2, ea);
        float d3 = xr.w - d.w * rx.w; ea = fmaf(d3, d3, ea);
      }
      ea += __shfl_xor(ea, 16, 64);
      ea += __shfl_xor(ea, 32, 64);
      if (q == 0) sLLE[p] = ea;
    }
    __syncthreads();
  }

  // ===== final F(511): elbo contribution only ==============================
  if (wid == 0) {
    float lw0 = 0, lw1 = 0;
#pragma unroll
    for (int half = 0; half < 2; ++half) {
      int j = 2 * lane + half;
      float v = -0.5f * sLLE[j] + cobs + cc1 + sLLD[j];
      if (half) lw1 = v; else lw0 = v;
    }
    float mx = fmaxf(lw0, lw1);
#pragma unroll
    for (int d = 32; d >= 1; d >>= 1) mx = fmaxf(mx, __shfl_xor(mx, d, 64));
    float se = __expf(lw0 - mx) + __expf(lw1 - mx);
#pragma unroll
    for (int d = 32; d >= 1; d >>= 1) se += __shfl_xor(se, d, 64);
    elbo += logf(se) + mx - 4.85203026f;
  }
  if (tid == 0) out[b] = -elbo * (1.0f / 512.0f);
}

extern "C" void kernel_launch(void* const* d_in, const int* in_sizes, int n_in,
                              void* d_out, int out_size, void* d_ws, size_t ws_size,
                              hipStream_t stream) {
  const float* x     = (const float*)d_in[0];
  const float* u     = (const float*)d_in[1];
  const float* R_z   = (const float*)d_in[2];
  const float* R_z0  = (const float*)d_in[3];
  const float* R_x   = (const float*)d_in[4];
  const float* B_obs = (const float*)d_in[5];
  const float* Obias = (const float*)d_in[6];
  const float* m     = (const float*)d_in[7];
  const float* n     = (const float*)d_in[8];
  const float* Wu    = (const float*)d_in[9];
  const float* h     = (const float*)d_in[10];
  const float* W0    = (const float*)d_in[11];
  const float* b0    = (const float*)d_in[12];
  float* ws = (float*)d_ws;
  float* outp = (float*)d_out;

  precomp_kernel<<<dim3(1), dim3(256), 0, stream>>>(R_z, R_z0, R_x, B_obs, ws);
  pf_kernel<<<dim3(128), dim3(512), 0, stream>>>(x, u, B_obs, Obias, m, n, Wu, h,
                                                 W0, b0, ws, outp);
}